// Round 2
// baseline (751.018 us; speedup 1.0000x reference)
//
#include <hip/hip_runtime.h>

// ---------------------------------------------------------------------------
// MultiHeadAttention: B=2, S=2048, D=1024, H=16, hd=64
// Interleaved head split: Q[b,h,s,d] = proj[b,s, d*16+h]; scale = 1/32.
// Precision strategy: scores need ~fp32 accuracy (softmax is near-argmax with
// sigma_score~256). Q,K path uses split-bf16 (hi+lo) emulated-fp32 MFMA:
//   A.B ~= Ahi.Bhi + Ahi.Blo + Alo.Bhi   (lo.lo dropped, ~2^-17 rel)
// V / attn / output projection stay plain bf16 (additive error ~10 << 103).
// ---------------------------------------------------------------------------

typedef __bf16 bf16x8 __attribute__((ext_vector_type(8)));
typedef __bf16 bf16x4 __attribute__((ext_vector_type(4)));
typedef float  f32x4  __attribute__((ext_vector_type(4)));

#define S_LEN  2048
#define DMODEL 1024
#define NHEADS 16
#define HDIM   64

// ---------------------------------------------------------------------------
// f32 -> (hi, lo) bf16 split, vectorized
// ---------------------------------------------------------------------------
__global__ __launch_bounds__(256) void conv_split(const float* __restrict__ x,
                                                  __bf16* __restrict__ hi,
                                                  __bf16* __restrict__ lo, int n4) {
    int i = blockIdx.x * 256 + threadIdx.x;
    if (i >= n4) return;
    float4 v = ((const float4*)x)[i];
    bf16x4 h, l;
#pragma unroll
    for (int c = 0; c < 4; c++) {
        float f = (&v.x)[c];
        __bf16 fh = (__bf16)f;
        h[c] = fh;
        l[c] = (__bf16)(f - (float)fh);
    }
    ((bf16x4*)hi)[i] = h;
    ((bf16x4*)lo)[i] = l;
}

// ---------------------------------------------------------------------------
// w[K=1024][N=1024] f32 -> wt[N][K] (hi, lo) bf16 split transpose
// ---------------------------------------------------------------------------
__global__ __launch_bounds__(256) void transpose_split(const float* __restrict__ w,
                                                       __bf16* __restrict__ wthi,
                                                       __bf16* __restrict__ wtlo) {
    __shared__ float tile[32][33];
    int n0 = blockIdx.x * 32, k0 = blockIdx.y * 32;
    int tx = threadIdx.x & 31, ty = threadIdx.x >> 5;
#pragma unroll
    for (int i = 0; i < 32; i += 8)
        tile[ty + i][tx] = w[(k0 + ty + i) * DMODEL + n0 + tx];
    __syncthreads();
#pragma unroll
    for (int i = 0; i < 32; i += 8) {
        float f = tile[tx][ty + i];
        __bf16 fh = (__bf16)f;
        wthi[(n0 + ty + i) * DMODEL + k0 + tx] = fh;
        wtlo[(n0 + ty + i) * DMODEL + k0 + tx] = (__bf16)(f - (float)fh);
    }
}

// plain bf16 transpose (for vw, ow)
__global__ __launch_bounds__(256) void transpose_bf16(const float* __restrict__ w,
                                                      __bf16* __restrict__ wt) {
    __shared__ float tile[32][33];
    int n0 = blockIdx.x * 32, k0 = blockIdx.y * 32;
    int tx = threadIdx.x & 31, ty = threadIdx.x >> 5;
#pragma unroll
    for (int i = 0; i < 32; i += 8)
        tile[ty + i][tx] = w[(k0 + ty + i) * DMODEL + n0 + tx];
    __syncthreads();
#pragma unroll
    for (int i = 0; i < 32; i += 8)
        wt[(n0 + ty + i) * DMODEL + k0 + tx] = (__bf16)tile[tx][ty + i];
}

// ---------------------------------------------------------------------------
// Split-bf16 GEMM: C = (Ahi+Alo) @ (Bhi+Blo)^T  (lo.lo dropped), fp32 accum.
// Output: Q/K layout [((b*16+h)*2048+s)*64+d], split into (hi, lo) bf16.
// 128x128 tile, BK=32, 4 waves, 4x4 16x16x32 frags per wave.
// ---------------------------------------------------------------------------
__global__ __launch_bounds__(256) void gemm_split(const __bf16* __restrict__ Ahi,
                                                  const __bf16* __restrict__ Alo,
                                                  const __bf16* __restrict__ Bthi,
                                                  const __bf16* __restrict__ Btlo,
                                                  __bf16* __restrict__ Ohi,
                                                  __bf16* __restrict__ Olo,
                                                  int M, int N, int K, float oscale) {
    __shared__ __bf16 Ash[128][40], Asl[128][40], Bsh[128][40], Bsl[128][40];
    int tid  = threadIdx.x;
    int wave = tid >> 6, lane = tid & 63;
    int quad = lane >> 4, l15 = lane & 15;
    int m0 = blockIdx.y * 128, n0 = blockIdx.x * 128;
    int wm = (wave >> 1) * 64, wn = (wave & 1) * 64;
    f32x4 acc[4][4] = {};

    int r = tid >> 2, c = (tid & 3) * 8;
    for (int k0 = 0; k0 < K; k0 += 32) {
        __syncthreads();
        *(uint4*)&Ash[r][c]      = *(const uint4*)&Ahi[(m0 + r) * K + k0 + c];
        *(uint4*)&Ash[r + 64][c] = *(const uint4*)&Ahi[(m0 + r + 64) * K + k0 + c];
        *(uint4*)&Asl[r][c]      = *(const uint4*)&Alo[(m0 + r) * K + k0 + c];
        *(uint4*)&Asl[r + 64][c] = *(const uint4*)&Alo[(m0 + r + 64) * K + k0 + c];
        *(uint4*)&Bsh[r][c]      = *(const uint4*)&Bthi[(n0 + r) * K + k0 + c];
        *(uint4*)&Bsh[r + 64][c] = *(const uint4*)&Bthi[(n0 + r + 64) * K + k0 + c];
        *(uint4*)&Bsl[r][c]      = *(const uint4*)&Btlo[(n0 + r) * K + k0 + c];
        *(uint4*)&Bsl[r + 64][c] = *(const uint4*)&Btlo[(n0 + r + 64) * K + k0 + c];
        __syncthreads();
        bf16x8 ah[4], al[4], bh[4], bl[4];
#pragma unroll
        for (int mi = 0; mi < 4; mi++) {
            ah[mi] = *(const bf16x8*)&Ash[wm + mi * 16 + l15][quad * 8];
            al[mi] = *(const bf16x8*)&Asl[wm + mi * 16 + l15][quad * 8];
        }
#pragma unroll
        for (int ni = 0; ni < 4; ni++) {
            bh[ni] = *(const bf16x8*)&Bsh[wn + ni * 16 + l15][quad * 8];
            bl[ni] = *(const bf16x8*)&Bsl[wn + ni * 16 + l15][quad * 8];
        }
#pragma unroll
        for (int mi = 0; mi < 4; mi++)
#pragma unroll
            for (int ni = 0; ni < 4; ni++) {
                acc[mi][ni] = __builtin_amdgcn_mfma_f32_16x16x32_bf16(ah[mi], bh[ni], acc[mi][ni], 0, 0, 0);
                acc[mi][ni] = __builtin_amdgcn_mfma_f32_16x16x32_bf16(ah[mi], bl[ni], acc[mi][ni], 0, 0, 0);
                acc[mi][ni] = __builtin_amdgcn_mfma_f32_16x16x32_bf16(al[mi], bh[ni], acc[mi][ni], 0, 0, 0);
            }
    }

#pragma unroll
    for (int mi = 0; mi < 4; mi++)
#pragma unroll
        for (int ni = 0; ni < 4; ni++)
#pragma unroll
            for (int rg = 0; rg < 4; rg++) {
                int m = m0 + wm + mi * 16 + quad * 4 + rg;
                int n = n0 + wn + ni * 16 + l15;
                float v = acc[mi][ni][rg] * oscale;
                int b = m >> 11, s = m & 2047;
                int h = n & 15,  d = n >> 4;
                size_t idx = ((size_t)(b * NHEADS + h) * S_LEN + s) * HDIM + d;
                __bf16 vh = (__bf16)v;
                Ohi[idx] = vh;
                Olo[idx] = (__bf16)(v - (float)vh);
            }
}

// ---------------------------------------------------------------------------
// Plain bf16 GEMM: C[M,N] = A[M,K] @ Bt[N,K]^T.
// MODE 0: fp32 row-major out.  MODE 2: bf16 V^T layout [((b*16+h)*64+d)*2048+s]
// ---------------------------------------------------------------------------
template <int MODE>
__global__ __launch_bounds__(256) void gemm_bt(const __bf16* __restrict__ A,
                                               const __bf16* __restrict__ Bt,
                                               void* __restrict__ outp,
                                               int M, int N, int K, float oscale) {
    __shared__ __bf16 As[128][40];
    __shared__ __bf16 Bs[128][40];
    int tid  = threadIdx.x;
    int wave = tid >> 6, lane = tid & 63;
    int quad = lane >> 4, l15 = lane & 15;
    int m0 = blockIdx.y * 128, n0 = blockIdx.x * 128;
    int wm = (wave >> 1) * 64, wn = (wave & 1) * 64;
    f32x4 acc[4][4] = {};

    int r = tid >> 2, c = (tid & 3) * 8;
    for (int k0 = 0; k0 < K; k0 += 32) {
        __syncthreads();
        *(uint4*)&As[r][c]      = *(const uint4*)&A[(m0 + r) * K + k0 + c];
        *(uint4*)&As[r + 64][c] = *(const uint4*)&A[(m0 + r + 64) * K + k0 + c];
        *(uint4*)&Bs[r][c]      = *(const uint4*)&Bt[(n0 + r) * K + k0 + c];
        *(uint4*)&Bs[r + 64][c] = *(const uint4*)&Bt[(n0 + r + 64) * K + k0 + c];
        __syncthreads();
        bf16x8 af[4], bfr[4];
#pragma unroll
        for (int mi = 0; mi < 4; mi++)
            af[mi] = *(const bf16x8*)&As[wm + mi * 16 + l15][quad * 8];
#pragma unroll
        for (int ni = 0; ni < 4; ni++)
            bfr[ni] = *(const bf16x8*)&Bs[wn + ni * 16 + l15][quad * 8];
#pragma unroll
        for (int mi = 0; mi < 4; mi++)
#pragma unroll
            for (int ni = 0; ni < 4; ni++)
                acc[mi][ni] = __builtin_amdgcn_mfma_f32_16x16x32_bf16(
                    af[mi], bfr[ni], acc[mi][ni], 0, 0, 0);
    }

#pragma unroll
    for (int mi = 0; mi < 4; mi++)
#pragma unroll
        for (int ni = 0; ni < 4; ni++)
#pragma unroll
            for (int rg = 0; rg < 4; rg++) {
                int m = m0 + wm + mi * 16 + quad * 4 + rg;
                int n = n0 + wn + ni * 16 + l15;
                float v = acc[mi][ni][rg] * oscale;
                if (MODE == 0) {
                    ((float*)outp)[(size_t)m * N + n] = v;
                } else {
                    int b = m >> 11, s = m & 2047;
                    int h = n & 15,  d = n >> 4;
                    ((__bf16*)outp)[((size_t)(b * NHEADS + h) * HDIM + d) * S_LEN + s] = (__bf16)v;
                }
            }
}

// ---------------------------------------------------------------------------
// Flash attention (causal, online softmax), split-bf16 QK^T.
// Qhi/Qlo, Khi/Klo: [B*H][S][64] bf16 (Q pre-scaled by 1/32).
// Vt: [B*H][64][S] bf16. Grid: (S/64, H, B); 4 waves x 16 q-rows.
// Output: merged [B,S,D] bf16, channel = d*16+h.
// ---------------------------------------------------------------------------
__global__ __launch_bounds__(256) void flash_attn(const __bf16* __restrict__ Qhi,
                                                  const __bf16* __restrict__ Qlo,
                                                  const __bf16* __restrict__ Khi,
                                                  const __bf16* __restrict__ Klo,
                                                  const __bf16* __restrict__ Vt,
                                                  __bf16* __restrict__ attn) {
    int qtile = blockIdx.x, h = blockIdx.y, b = blockIdx.z;
    int bh = b * NHEADS + h;
    const __bf16* Qhh = Qhi + (size_t)bh * S_LEN * HDIM;
    const __bf16* Qlh = Qlo + (size_t)bh * S_LEN * HDIM;
    const __bf16* Khh = Khi + (size_t)bh * S_LEN * HDIM;
    const __bf16* Klh = Klo + (size_t)bh * S_LEN * HDIM;
    const __bf16* Vh  = Vt  + (size_t)bh * HDIM * S_LEN;
    int tid = threadIdx.x, wave = tid >> 6, lane = tid & 63;
    int quad = lane >> 4, l15 = lane & 15;
    int q0 = qtile * 64, qw0 = q0 + wave * 16;
    int qrow_base = qw0 + quad * 4;

    __shared__ __bf16 Ps[4][16][72];

    bf16x8 aqh0 = *(const bf16x8*)&Qhh[(qw0 + l15) * HDIM + quad * 8];
    bf16x8 aqh1 = *(const bf16x8*)&Qhh[(qw0 + l15) * HDIM + 32 + quad * 8];
    bf16x8 aql0 = *(const bf16x8*)&Qlh[(qw0 + l15) * HDIM + quad * 8];
    bf16x8 aql1 = *(const bf16x8*)&Qlh[(qw0 + l15) * HDIM + 32 + quad * 8];

    f32x4 o[4] = {};
    float mrow[4] = {-INFINITY, -INFINITY, -INFINITY, -INFINITY};
    float lrow[4] = {0.f, 0.f, 0.f, 0.f};

    for (int kt = 0; kt <= qtile; kt++) {
        int key0 = kt * 64;
        // ---- S = (Q/32) K^T, split-bf16: hi.hi + hi.lo + lo.hi
        f32x4 sc[4] = {};
#pragma unroll
        for (int ni = 0; ni < 4; ni++) {
            size_t koff = (size_t)(key0 + ni * 16 + l15) * HDIM;
            bf16x8 kh0 = *(const bf16x8*)&Khh[koff + quad * 8];
            bf16x8 kh1 = *(const bf16x8*)&Khh[koff + 32 + quad * 8];
            bf16x8 kl0 = *(const bf16x8*)&Klh[koff + quad * 8];
            bf16x8 kl1 = *(const bf16x8*)&Klh[koff + 32 + quad * 8];
            sc[ni] = __builtin_amdgcn_mfma_f32_16x16x32_bf16(aqh0, kh0, sc[ni], 0, 0, 0);
            sc[ni] = __builtin_amdgcn_mfma_f32_16x16x32_bf16(aqh1, kh1, sc[ni], 0, 0, 0);
            sc[ni] = __builtin_amdgcn_mfma_f32_16x16x32_bf16(aqh0, kl0, sc[ni], 0, 0, 0);
            sc[ni] = __builtin_amdgcn_mfma_f32_16x16x32_bf16(aqh1, kl1, sc[ni], 0, 0, 0);
            sc[ni] = __builtin_amdgcn_mfma_f32_16x16x32_bf16(aql0, kh0, sc[ni], 0, 0, 0);
            sc[ni] = __builtin_amdgcn_mfma_f32_16x16x32_bf16(aql1, kh1, sc[ni], 0, 0, 0);
        }
        // ---- causal mask + online softmax
#pragma unroll
        for (int rg = 0; rg < 4; rg++) {
            int qrow = qrow_base + rg;
            float vals[4];
            float mx = -INFINITY;
#pragma unroll
            for (int ni = 0; ni < 4; ni++) {
                int key = key0 + ni * 16 + l15;
                float v = sc[ni][rg];
                if (key > qrow) v = -1e30f;
                vals[ni] = v;
                mx = fmaxf(mx, v);
            }
#pragma unroll
            for (int mm = 1; mm < 16; mm <<= 1)
                mx = fmaxf(mx, __shfl_xor(mx, mm, 64));
            float mnew  = fmaxf(mrow[rg], mx);
            float alpha = __expf(mrow[rg] - mnew);
            mrow[rg] = mnew;
            float rsum = 0.f;
#pragma unroll
            for (int ni = 0; ni < 4; ni++) {
                float p = __expf(vals[ni] - mnew);
                sc[ni][rg] = p;
                rsum += p;
            }
#pragma unroll
            for (int mm = 1; mm < 16; mm <<= 1)
                rsum += __shfl_xor(rsum, mm, 64);
            lrow[rg] = lrow[rg] * alpha + rsum;
#pragma unroll
            for (int ni = 0; ni < 4; ni++)
                o[ni][rg] *= alpha;
        }
        // ---- P: C-layout -> A-layout via LDS
#pragma unroll
        for (int ni = 0; ni < 4; ni++)
#pragma unroll
            for (int rg = 0; rg < 4; rg++)
                Ps[wave][quad * 4 + rg][ni * 16 + l15] = (__bf16)sc[ni][rg];
        __syncthreads();
        // ---- O += P @ V
#pragma unroll
        for (int step = 0; step < 2; step++) {
            bf16x8 ap = *(const bf16x8*)&Ps[wave][l15][step * 32 + quad * 8];
#pragma unroll
            for (int ni = 0; ni < 4; ni++) {
                bf16x8 bv = *(const bf16x8*)&Vh[(ni * 16 + l15) * S_LEN + key0 + step * 32 + quad * 8];
                o[ni] = __builtin_amdgcn_mfma_f32_16x16x32_bf16(ap, bv, o[ni], 0, 0, 0);
            }
        }
        __syncthreads();
    }
    // ---- epilogue
#pragma unroll
    for (int rg = 0; rg < 4; rg++) {
        float inv = 1.0f / lrow[rg];
        int q = qrow_base + rg;
#pragma unroll
        for (int ni = 0; ni < 4; ni++) {
            int d = ni * 16 + l15;
            attn[((size_t)b * S_LEN + q) * DMODEL + d * NHEADS + h] = (__bf16)(o[ni][rg] * inv);
        }
    }
}

// ---------------------------------------------------------------------------
extern "C" void kernel_launch(void* const* d_in, const int* in_sizes, int n_in,
                              void* d_out, int out_size, void* d_ws, size_t ws_size,
                              hipStream_t stream) {
    const float* x  = (const float*)d_in[0];
    const float* qw = (const float*)d_in[1];
    const float* kw = (const float*)d_in[2];
    const float* vw = (const float*)d_in[3];
    const float* ow = (const float*)d_in[4];

    char* ws = (char*)d_ws;
    const size_t MB = 1024 * 1024;
    __bf16* xhi   = (__bf16*)(ws);             //  8 MB  [4096,1024]
    __bf16* xlo   = (__bf16*)(ws + 8 * MB);    //  8 MB  (reused as attnb later)
    __bf16* qwthi = (__bf16*)(ws + 16 * MB);   //  2 MB each
    __bf16* qwtlo = (__bf16*)(ws + 18 * MB);
    __bf16* kwthi = (__bf16*)(ws + 20 * MB);
    __bf16* kwtlo = (__bf16*)(ws + 22 * MB);
    __bf16* vwt   = (__bf16*)(ws + 24 * MB);
    __bf16* owt   = (__bf16*)(ws + 26 * MB);
    __bf16* Qhi_b = (__bf16*)(ws + 28 * MB);   //  8 MB  [B,H,S,64]
    __bf16* Qlo_b = (__bf16*)(ws + 36 * MB);
    __bf16* Khi_b = (__bf16*)(ws + 44 * MB);
    __bf16* Klo_b = (__bf16*)(ws + 52 * MB);
    __bf16* Vtb   = (__bf16*)(ws + 60 * MB);   //  8 MB  [B,H,64,S]
    __bf16* attnb = xlo;                       //  alias: xlo dead after Q/K GEMMs

    conv_split<<<4096, 256, 0, stream>>>(x, xhi, xlo, 4096 * 1024 / 4);
    dim3 tg(32, 32);
    transpose_split<<<tg, 256, 0, stream>>>(qw, qwthi, qwtlo);
    transpose_split<<<tg, 256, 0, stream>>>(kw, kwthi, kwtlo);
    transpose_bf16<<<tg, 256, 0, stream>>>(vw, vwt);
    transpose_bf16<<<tg, 256, 0, stream>>>(ow, owt);

    dim3 gg(DMODEL / 128, 4096 / 128);  // (8, 32)
    gemm_split<<<gg, 256, 0, stream>>>(xhi, xlo, qwthi, qwtlo, Qhi_b, Qlo_b,
                                       4096, 1024, 1024, 0.03125f);
    gemm_split<<<gg, 256, 0, stream>>>(xhi, xlo, kwthi, kwtlo, Khi_b, Klo_b,
                                       4096, 1024, 1024, 1.0f);
    gemm_bt<2><<<gg, 256, 0, stream>>>(xhi, vwt, Vtb, 4096, 1024, 1024, 1.0f);

    flash_attn<<<dim3(S_LEN / 64, NHEADS, 2), 256, 0, stream>>>(
        Qhi_b, Qlo_b, Khi_b, Klo_b, Vtb, attnb);

    gemm_bt<0><<<gg, 256, 0, stream>>>(attnb, owt, d_out, 4096, 1024, 1024, 1.0f);
}

// Round 3
// 518.846 us; speedup vs baseline: 1.4475x; 1.4475x over previous
//
#include <hip/hip_runtime.h>

// ---------------------------------------------------------------------------
// MultiHeadAttention: B=2, S=2048, D=1024, H=16, hd=64
// Interleaved head split: Q[b,h,s,d] = proj[b,s, d*16+h]; scale = 1/32.
// Precision: split-bf16 (hi+lo) emulated-fp32 for the Q/K path (softmax is
// near-argmax, sigma_score~256, needs ~fp32 scores). V/attn/out-proj plain bf16.
// Flash v2: per-wave 16-row q-tiles, paired (t, 127-t) for perfect causal
// balance (33 kt-iters/wave), 2-way key-split (kt parity) for 2x waves,
// no barriers in the hot loop, one combine via LDS at the end.
// ---------------------------------------------------------------------------

typedef __bf16 bf16x8 __attribute__((ext_vector_type(8)));
typedef __bf16 bf16x4 __attribute__((ext_vector_type(4)));
typedef float  f32x4  __attribute__((ext_vector_type(4)));

#define S_LEN  2048
#define DMODEL 1024
#define NHEADS 16
#define HDIM   64

// ---------------------------------------------------------------------------
// f32 -> (hi, lo) bf16 split, vectorized
// ---------------------------------------------------------------------------
__global__ __launch_bounds__(256) void conv_split(const float* __restrict__ x,
                                                  __bf16* __restrict__ hi,
                                                  __bf16* __restrict__ lo, int n4) {
    int i = blockIdx.x * 256 + threadIdx.x;
    if (i >= n4) return;
    float4 v = ((const float4*)x)[i];
    bf16x4 h, l;
#pragma unroll
    for (int c = 0; c < 4; c++) {
        float f = (&v.x)[c];
        __bf16 fh = (__bf16)f;
        h[c] = fh;
        l[c] = (__bf16)(f - (float)fh);
    }
    ((bf16x4*)hi)[i] = h;
    ((bf16x4*)lo)[i] = l;
}

// ---------------------------------------------------------------------------
// w[K=1024][N=1024] f32 -> wt[N][K] (hi, lo) bf16 split transpose
// ---------------------------------------------------------------------------
__global__ __launch_bounds__(256) void transpose_split(const float* __restrict__ w,
                                                       __bf16* __restrict__ wthi,
                                                       __bf16* __restrict__ wtlo) {
    __shared__ float tile[32][33];
    int n0 = blockIdx.x * 32, k0 = blockIdx.y * 32;
    int tx = threadIdx.x & 31, ty = threadIdx.x >> 5;
#pragma unroll
    for (int i = 0; i < 32; i += 8)
        tile[ty + i][tx] = w[(k0 + ty + i) * DMODEL + n0 + tx];
    __syncthreads();
#pragma unroll
    for (int i = 0; i < 32; i += 8) {
        float f = tile[tx][ty + i];
        __bf16 fh = (__bf16)f;
        wthi[(n0 + ty + i) * DMODEL + k0 + tx] = fh;
        wtlo[(n0 + ty + i) * DMODEL + k0 + tx] = (__bf16)(f - (float)fh);
    }
}

// plain bf16 transpose (for vw, ow)
__global__ __launch_bounds__(256) void transpose_bf16(const float* __restrict__ w,
                                                      __bf16* __restrict__ wt) {
    __shared__ float tile[32][33];
    int n0 = blockIdx.x * 32, k0 = blockIdx.y * 32;
    int tx = threadIdx.x & 31, ty = threadIdx.x >> 5;
#pragma unroll
    for (int i = 0; i < 32; i += 8)
        tile[ty + i][tx] = w[(k0 + ty + i) * DMODEL + n0 + tx];
    __syncthreads();
#pragma unroll
    for (int i = 0; i < 32; i += 8)
        wt[(n0 + ty + i) * DMODEL + k0 + tx] = (__bf16)tile[tx][ty + i];
}

// ---------------------------------------------------------------------------
// Split-bf16 GEMM: C = (Ahi+Alo) @ (Bhi+Blo)^T  (lo.lo dropped), fp32 accum.
// Output: Q/K layout [((b*16+h)*2048+s)*64+d], split into (hi, lo) bf16.
// ---------------------------------------------------------------------------
__global__ __launch_bounds__(256) void gemm_split(const __bf16* __restrict__ Ahi,
                                                  const __bf16* __restrict__ Alo,
                                                  const __bf16* __restrict__ Bthi,
                                                  const __bf16* __restrict__ Btlo,
                                                  __bf16* __restrict__ Ohi,
                                                  __bf16* __restrict__ Olo,
                                                  int M, int N, int K, float oscale) {
    __shared__ __bf16 Ash[128][40], Asl[128][40], Bsh[128][40], Bsl[128][40];
    int tid  = threadIdx.x;
    int wave = tid >> 6, lane = tid & 63;
    int quad = lane >> 4, l15 = lane & 15;
    int m0 = blockIdx.y * 128, n0 = blockIdx.x * 128;
    int wm = (wave >> 1) * 64, wn = (wave & 1) * 64;
    f32x4 acc[4][4] = {};

    int r = tid >> 2, c = (tid & 3) * 8;
    for (int k0 = 0; k0 < K; k0 += 32) {
        __syncthreads();
        *(uint4*)&Ash[r][c]      = *(const uint4*)&Ahi[(m0 + r) * K + k0 + c];
        *(uint4*)&Ash[r + 64][c] = *(const uint4*)&Ahi[(m0 + r + 64) * K + k0 + c];
        *(uint4*)&Asl[r][c]      = *(const uint4*)&Alo[(m0 + r) * K + k0 + c];
        *(uint4*)&Asl[r + 64][c] = *(const uint4*)&Alo[(m0 + r + 64) * K + k0 + c];
        *(uint4*)&Bsh[r][c]      = *(const uint4*)&Bthi[(n0 + r) * K + k0 + c];
        *(uint4*)&Bsh[r + 64][c] = *(const uint4*)&Bthi[(n0 + r + 64) * K + k0 + c];
        *(uint4*)&Bsl[r][c]      = *(const uint4*)&Btlo[(n0 + r) * K + k0 + c];
        *(uint4*)&Bsl[r + 64][c] = *(const uint4*)&Btlo[(n0 + r + 64) * K + k0 + c];
        __syncthreads();
        bf16x8 ah[4], al[4], bh[4], bl[4];
#pragma unroll
        for (int mi = 0; mi < 4; mi++) {
            ah[mi] = *(const bf16x8*)&Ash[wm + mi * 16 + l15][quad * 8];
            al[mi] = *(const bf16x8*)&Asl[wm + mi * 16 + l15][quad * 8];
        }
#pragma unroll
        for (int ni = 0; ni < 4; ni++) {
            bh[ni] = *(const bf16x8*)&Bsh[wn + ni * 16 + l15][quad * 8];
            bl[ni] = *(const bf16x8*)&Bsl[wn + ni * 16 + l15][quad * 8];
        }
#pragma unroll
        for (int mi = 0; mi < 4; mi++)
#pragma unroll
            for (int ni = 0; ni < 4; ni++) {
                acc[mi][ni] = __builtin_amdgcn_mfma_f32_16x16x32_bf16(ah[mi], bh[ni], acc[mi][ni], 0, 0, 0);
                acc[mi][ni] = __builtin_amdgcn_mfma_f32_16x16x32_bf16(ah[mi], bl[ni], acc[mi][ni], 0, 0, 0);
                acc[mi][ni] = __builtin_amdgcn_mfma_f32_16x16x32_bf16(al[mi], bh[ni], acc[mi][ni], 0, 0, 0);
            }
    }

#pragma unroll
    for (int mi = 0; mi < 4; mi++)
#pragma unroll
        for (int ni = 0; ni < 4; ni++)
#pragma unroll
            for (int rg = 0; rg < 4; rg++) {
                int m = m0 + wm + mi * 16 + quad * 4 + rg;
                int n = n0 + wn + ni * 16 + l15;
                float v = acc[mi][ni][rg] * oscale;
                int b = m >> 11, s = m & 2047;
                int h = n & 15,  d = n >> 4;
                size_t idx = ((size_t)(b * NHEADS + h) * S_LEN + s) * HDIM + d;
                __bf16 vh = (__bf16)v;
                Ohi[idx] = vh;
                Olo[idx] = (__bf16)(v - (float)vh);
            }
}

// ---------------------------------------------------------------------------
// Plain bf16 GEMM: C[M,N] = A[M,K] @ Bt[N,K]^T.
// MODE 0: fp32 row-major out.  MODE 2: bf16 V^T layout [((b*16+h)*64+d)*2048+s]
// ---------------------------------------------------------------------------
template <int MODE>
__global__ __launch_bounds__(256) void gemm_bt(const __bf16* __restrict__ A,
                                               const __bf16* __restrict__ Bt,
                                               void* __restrict__ outp,
                                               int M, int N, int K, float oscale) {
    __shared__ __bf16 As[128][40];
    __shared__ __bf16 Bs[128][40];
    int tid  = threadIdx.x;
    int wave = tid >> 6, lane = tid & 63;
    int quad = lane >> 4, l15 = lane & 15;
    int m0 = blockIdx.y * 128, n0 = blockIdx.x * 128;
    int wm = (wave >> 1) * 64, wn = (wave & 1) * 64;
    f32x4 acc[4][4] = {};

    int r = tid >> 2, c = (tid & 3) * 8;
    for (int k0 = 0; k0 < K; k0 += 32) {
        __syncthreads();
        *(uint4*)&As[r][c]      = *(const uint4*)&A[(m0 + r) * K + k0 + c];
        *(uint4*)&As[r + 64][c] = *(const uint4*)&A[(m0 + r + 64) * K + k0 + c];
        *(uint4*)&Bs[r][c]      = *(const uint4*)&Bt[(n0 + r) * K + k0 + c];
        *(uint4*)&Bs[r + 64][c] = *(const uint4*)&Bt[(n0 + r + 64) * K + k0 + c];
        __syncthreads();
        bf16x8 af[4], bfr[4];
#pragma unroll
        for (int mi = 0; mi < 4; mi++)
            af[mi] = *(const bf16x8*)&As[wm + mi * 16 + l15][quad * 8];
#pragma unroll
        for (int ni = 0; ni < 4; ni++)
            bfr[ni] = *(const bf16x8*)&Bs[wn + ni * 16 + l15][quad * 8];
#pragma unroll
        for (int mi = 0; mi < 4; mi++)
#pragma unroll
            for (int ni = 0; ni < 4; ni++)
                acc[mi][ni] = __builtin_amdgcn_mfma_f32_16x16x32_bf16(
                    af[mi], bfr[ni], acc[mi][ni], 0, 0, 0);
    }

#pragma unroll
    for (int mi = 0; mi < 4; mi++)
#pragma unroll
        for (int ni = 0; ni < 4; ni++)
#pragma unroll
            for (int rg = 0; rg < 4; rg++) {
                int m = m0 + wm + mi * 16 + quad * 4 + rg;
                int n = n0 + wn + ni * 16 + l15;
                float v = acc[mi][ni][rg] * oscale;
                if (MODE == 0) {
                    ((float*)outp)[(size_t)m * N + n] = v;
                } else {
                    int b = m >> 11, s = m & 2047;
                    int h = n & 15,  d = n >> 4;
                    ((__bf16*)outp)[((size_t)(b * NHEADS + h) * HDIM + d) * S_LEN + s] = (__bf16)v;
                }
            }
}

// ---------------------------------------------------------------------------
// Flash attention v2 — per-wave 16-row q-tile, split-bf16 QK^T, causal.
// One wave processes one q-tile's keys of one kt-parity (2-way key split).
// No barriers in the hot loop (Ps slice is wave-private).
// ---------------------------------------------------------------------------
__device__ __forceinline__ void fa_tile(const __bf16* __restrict__ Qhh,
                                        const __bf16* __restrict__ Qlh,
                                        const __bf16* __restrict__ Khh,
                                        const __bf16* __restrict__ Klh,
                                        const __bf16* __restrict__ Vh,
                                        __bf16 (*PsW)[72],
                                        int T, int split, int quad, int l15,
                                        float (&mrow)[4], float (&lrow)[4],
                                        f32x4 (&o)[4]) {
    const int q0 = T * 16;
    const int qrow_base = q0 + quad * 4;
    bf16x8 aqh0 = *(const bf16x8*)&Qhh[(q0 + l15) * HDIM + quad * 8];
    bf16x8 aqh1 = *(const bf16x8*)&Qhh[(q0 + l15) * HDIM + 32 + quad * 8];
    bf16x8 aql0 = *(const bf16x8*)&Qlh[(q0 + l15) * HDIM + quad * 8];
    bf16x8 aql1 = *(const bf16x8*)&Qlh[(q0 + l15) * HDIM + 32 + quad * 8];
    const int kend = T >> 2;  // diagonal 64-key tile index

    for (int kt = split; kt <= kend; kt += 2) {
        int key0 = kt * 64;
        // ---- S = (Q/32) K^T, split-bf16: hi.hi + hi.lo + lo.hi
        f32x4 sc[4] = {};
#pragma unroll
        for (int ni = 0; ni < 4; ni++) {
            size_t koff = (size_t)(key0 + ni * 16 + l15) * HDIM;
            bf16x8 kh0 = *(const bf16x8*)&Khh[koff + quad * 8];
            bf16x8 kh1 = *(const bf16x8*)&Khh[koff + 32 + quad * 8];
            bf16x8 kl0 = *(const bf16x8*)&Klh[koff + quad * 8];
            bf16x8 kl1 = *(const bf16x8*)&Klh[koff + 32 + quad * 8];
            sc[ni] = __builtin_amdgcn_mfma_f32_16x16x32_bf16(aqh0, kh0, sc[ni], 0, 0, 0);
            sc[ni] = __builtin_amdgcn_mfma_f32_16x16x32_bf16(aqh1, kh1, sc[ni], 0, 0, 0);
            sc[ni] = __builtin_amdgcn_mfma_f32_16x16x32_bf16(aqh0, kl0, sc[ni], 0, 0, 0);
            sc[ni] = __builtin_amdgcn_mfma_f32_16x16x32_bf16(aqh1, kl1, sc[ni], 0, 0, 0);
            sc[ni] = __builtin_amdgcn_mfma_f32_16x16x32_bf16(aql0, kh0, sc[ni], 0, 0, 0);
            sc[ni] = __builtin_amdgcn_mfma_f32_16x16x32_bf16(aql1, kh1, sc[ni], 0, 0, 0);
        }
        // ---- causal mask + online softmax (rows live in 16-lane groups)
#pragma unroll
        for (int rg = 0; rg < 4; rg++) {
            int qrow = qrow_base + rg;
            float vals[4];
            float mx = -INFINITY;
#pragma unroll
            for (int ni = 0; ni < 4; ni++) {
                int key = key0 + ni * 16 + l15;
                float v = sc[ni][rg];
                if (key > qrow) v = -1e30f;
                vals[ni] = v;
                mx = fmaxf(mx, v);
            }
#pragma unroll
            for (int mm = 1; mm < 16; mm <<= 1)
                mx = fmaxf(mx, __shfl_xor(mx, mm, 64));
            float mnew  = fmaxf(mrow[rg], mx);
            float alpha = __expf(mrow[rg] - mnew);
            mrow[rg] = mnew;
            float rsum = 0.f;
#pragma unroll
            for (int ni = 0; ni < 4; ni++) {
                float p = __expf(vals[ni] - mnew);
                sc[ni][rg] = p;
                rsum += p;
            }
#pragma unroll
            for (int mm = 1; mm < 16; mm <<= 1)
                rsum += __shfl_xor(rsum, mm, 64);
            lrow[rg] = lrow[rg] * alpha + rsum;
#pragma unroll
            for (int ni = 0; ni < 4; ni++)
                o[ni][rg] *= alpha;
        }
        // ---- P: C-layout -> A-layout via wave-private LDS (no barrier)
#pragma unroll
        for (int ni = 0; ni < 4; ni++)
#pragma unroll
            for (int rg = 0; rg < 4; rg++)
                PsW[quad * 4 + rg][ni * 16 + l15] = (__bf16)sc[ni][rg];
        // ---- O += P @ V
#pragma unroll
        for (int step = 0; step < 2; step++) {
            bf16x8 ap = *(const bf16x8*)&PsW[l15][step * 32 + quad * 8];
#pragma unroll
            for (int ni = 0; ni < 4; ni++) {
                bf16x8 bv = *(const bf16x8*)&Vh[(ni * 16 + l15) * S_LEN + key0 + step * 32 + quad * 8];
                o[ni] = __builtin_amdgcn_mfma_f32_16x16x32_bf16(ap, bv, o[ni], 0, 0, 0);
            }
        }
    }
}

__global__ __launch_bounds__(256, 4) void flash_attn(const __bf16* __restrict__ Qhi,
                                                     const __bf16* __restrict__ Qlo,
                                                     const __bf16* __restrict__ Khi,
                                                     const __bf16* __restrict__ Klo,
                                                     const __bf16* __restrict__ Vt,
                                                     __bf16* __restrict__ attn) {
    int h = blockIdx.y, b = blockIdx.z;
    int bh = b * NHEADS + h;
    const __bf16* Qhh = Qhi + (size_t)bh * S_LEN * HDIM;
    const __bf16* Qlh = Qlo + (size_t)bh * S_LEN * HDIM;
    const __bf16* Khh = Khi + (size_t)bh * S_LEN * HDIM;
    const __bf16* Klh = Klo + (size_t)bh * S_LEN * HDIM;
    const __bf16* Vh  = Vt  + (size_t)bh * HDIM * S_LEN;
    int tid = threadIdx.x, wave = tid >> 6, lane = tid & 63;
    int quad = lane >> 4, l15 = lane & 15;
    int pib = wave >> 1, split = wave & 1;
    int p = blockIdx.x * 2 + pib;       // tile pair index 0..63
    int t1 = p, t2 = 127 - p;           // paired 16-row q-tiles (33 iters total)

    __shared__ __bf16 Ps[4][16][72];    // wave-private P round-trip
    __shared__ float cO[2][2][16][64];  // [pair][slot][row][dim] partials
    __shared__ float cM[2][2][16];
    __shared__ float cL[2][2][16];

    // Wave schedule: even (split=0) runs t2 then t1, merges t1 (slot0 from odd).
    //                odd  (split=1) runs t1 then t2, merges t2 (slot1 from even).
    int firstT = split ? t1 : t2;
    int mergT  = split ? t2 : t1;
    int slotW  = split ? 0 : 1;
    int slotR  = split ? 1 : 0;

    float m[4] = {-INFINITY, -INFINITY, -INFINITY, -INFINITY};
    float l[4] = {0.f, 0.f, 0.f, 0.f};
    f32x4 o[4] = {};

    fa_tile(Qhh, Qlh, Khh, Klh, Vh, Ps[wave], firstT, split, quad, l15, m, l, o);

    // stash first tile's partial (frees the accumulators for phase 2)
#pragma unroll
    for (int rg = 0; rg < 4; rg++) {
        int row = quad * 4 + rg;
#pragma unroll
        for (int ni = 0; ni < 4; ni++)
            cO[pib][slotW][row][ni * 16 + l15] = o[ni][rg];
        if (l15 == 0) { cM[pib][slotW][row] = m[rg]; cL[pib][slotW][row] = l[rg]; }
        m[rg] = -INFINITY;
        l[rg] = 0.f;
    }
#pragma unroll
    for (int ni = 0; ni < 4; ni++) o[ni] = (f32x4){0.f, 0.f, 0.f, 0.f};

    fa_tile(Qhh, Qlh, Khh, Klh, Vh, Ps[wave], mergT, split, quad, l15, m, l, o);

    __syncthreads();

    // merge own partial of mergT with the other wave's partial; write output
#pragma unroll
    for (int rg = 0; rg < 4; rg++) {
        int row = quad * 4 + rg;
        float mo  = cM[pib][slotR][row];
        float lo2 = cL[pib][slotR][row];
        float mm  = fmaxf(m[rg], mo);
        float a1  = __expf(m[rg] - mm);
        float a2  = __expf(mo - mm);
        float inv = 1.0f / (l[rg] * a1 + lo2 * a2);
        int q = mergT * 16 + row;
#pragma unroll
        for (int ni = 0; ni < 4; ni++) {
            int d = ni * 16 + l15;
            float val = (o[ni][rg] * a1 + cO[pib][slotR][row][d] * a2) * inv;
            attn[((size_t)b * S_LEN + q) * DMODEL + d * NHEADS + h] = (__bf16)val;
        }
    }
}

// ---------------------------------------------------------------------------
extern "C" void kernel_launch(void* const* d_in, const int* in_sizes, int n_in,
                              void* d_out, int out_size, void* d_ws, size_t ws_size,
                              hipStream_t stream) {
    const float* x  = (const float*)d_in[0];
    const float* qw = (const float*)d_in[1];
    const float* kw = (const float*)d_in[2];
    const float* vw = (const float*)d_in[3];
    const float* ow = (const float*)d_in[4];

    char* ws = (char*)d_ws;
    const size_t MB = 1024 * 1024;
    __bf16* xhi   = (__bf16*)(ws);             //  8 MB  [4096,1024]
    __bf16* xlo   = (__bf16*)(ws + 8 * MB);    //  8 MB  (reused as attnb later)
    __bf16* qwthi = (__bf16*)(ws + 16 * MB);   //  2 MB each
    __bf16* qwtlo = (__bf16*)(ws + 18 * MB);
    __bf16* kwthi = (__bf16*)(ws + 20 * MB);
    __bf16* kwtlo = (__bf16*)(ws + 22 * MB);
    __bf16* vwt   = (__bf16*)(ws + 24 * MB);
    __bf16* owt   = (__bf16*)(ws + 26 * MB);
    __bf16* Qhi_b = (__bf16*)(ws + 28 * MB);   //  8 MB  [B,H,S,64]
    __bf16* Qlo_b = (__bf16*)(ws + 36 * MB);
    __bf16* Khi_b = (__bf16*)(ws + 44 * MB);
    __bf16* Klo_b = (__bf16*)(ws + 52 * MB);
    __bf16* Vtb   = (__bf16*)(ws + 60 * MB);   //  8 MB  [B,H,64,S]
    __bf16* attnb = xlo;                       //  alias: xlo dead after Q/K GEMMs

    conv_split<<<4096, 256, 0, stream>>>(x, xhi, xlo, 4096 * 1024 / 4);
    dim3 tg(32, 32);
    transpose_split<<<tg, 256, 0, stream>>>(qw, qwthi, qwtlo);
    transpose_split<<<tg, 256, 0, stream>>>(kw, kwthi, kwtlo);
    transpose_bf16<<<tg, 256, 0, stream>>>(vw, vwt);
    transpose_bf16<<<tg, 256, 0, stream>>>(ow, owt);

    dim3 gg(DMODEL / 128, 4096 / 128);  // (8, 32)
    gemm_split<<<gg, 256, 0, stream>>>(xhi, xlo, qwthi, qwtlo, Qhi_b, Qlo_b,
                                       4096, 1024, 1024, 0.03125f);
    gemm_split<<<gg, 256, 0, stream>>>(xhi, xlo, kwthi, kwtlo, Khi_b, Klo_b,
                                       4096, 1024, 1024, 1.0f);
    gemm_bt<2><<<gg, 256, 0, stream>>>(xhi, vwt, Vtb, 4096, 1024, 1024, 1.0f);

    flash_attn<<<dim3(32, NHEADS, 2), 256, 0, stream>>>(
        Qhi_b, Qlo_b, Khi_b, Klo_b, Vtb, attnb);

    gemm_bt<0><<<gg, 256, 0, stream>>>(attnb, owt, d_out, 4096, 1024, 1024, 1.0f);
}

// Round 4
// 404.541 us; speedup vs baseline: 1.8565x; 1.2826x over previous
//
#include <hip/hip_runtime.h>

// ---------------------------------------------------------------------------
// MultiHeadAttention: B=2, S=2048, D=1024, H=16, hd=64
// Interleaved head split: Q[b,h,s,d] = proj[b,s, d*16+h]; scale = 1/32.
// Precision: split-bf16 (hi+lo) emulated-fp32 for Q/K path. V/attn/out plain bf16.
// Flash v3: block-cooperative. Block = 64-row q-tile pair (t, 31-t) -> 33
// kt-iters for all blocks. K/V staged in LDS (xor-swizzled, reg-prefetch
// double-buffer, 1 barrier/iter), shared by 4 waves. XCD-swizzled block ids
// pin 4 heads per XCD (working set 3MB < 4MB L2).
// GEMMs: m97-style global_load_lds width-16 staging, unpadded LDS tiles.
// ---------------------------------------------------------------------------

typedef __bf16 bf16x8 __attribute__((ext_vector_type(8)));
typedef __bf16 bf16x4 __attribute__((ext_vector_type(4)));
typedef float  f32x4  __attribute__((ext_vector_type(4)));

#define S_LEN  2048
#define DMODEL 1024
#define NHEADS 16
#define HDIM   64

__device__ __forceinline__ void gll16(const __bf16* g, __bf16* l) {
    __builtin_amdgcn_global_load_lds(
        (const __attribute__((address_space(1))) unsigned int*)g,
        (__attribute__((address_space(3))) unsigned int*)l, 16, 0, 0);
}

// ---------------------------------------------------------------------------
// f32 -> (hi, lo) bf16 split, vectorized
// ---------------------------------------------------------------------------
__global__ __launch_bounds__(256) void conv_split(const float* __restrict__ x,
                                                  __bf16* __restrict__ hi,
                                                  __bf16* __restrict__ lo, int n4) {
    int i = blockIdx.x * 256 + threadIdx.x;
    if (i >= n4) return;
    float4 v = ((const float4*)x)[i];
    bf16x4 h, l;
#pragma unroll
    for (int c = 0; c < 4; c++) {
        float f = (&v.x)[c];
        __bf16 fh = (__bf16)f;
        h[c] = fh;
        l[c] = (__bf16)(f - (float)fh);
    }
    ((bf16x4*)hi)[i] = h;
    ((bf16x4*)lo)[i] = l;
}

// ---------------------------------------------------------------------------
// w[K][N] f32 -> wt[N][K] (hi, lo) split transpose
// ---------------------------------------------------------------------------
__global__ __launch_bounds__(256) void transpose_split(const float* __restrict__ w,
                                                       __bf16* __restrict__ wthi,
                                                       __bf16* __restrict__ wtlo) {
    __shared__ float tile[32][33];
    int n0 = blockIdx.x * 32, k0 = blockIdx.y * 32;
    int tx = threadIdx.x & 31, ty = threadIdx.x >> 5;
#pragma unroll
    for (int i = 0; i < 32; i += 8)
        tile[ty + i][tx] = w[(k0 + ty + i) * DMODEL + n0 + tx];
    __syncthreads();
#pragma unroll
    for (int i = 0; i < 32; i += 8) {
        float f = tile[tx][ty + i];
        __bf16 fh = (__bf16)f;
        wthi[(n0 + ty + i) * DMODEL + k0 + tx] = fh;
        wtlo[(n0 + ty + i) * DMODEL + k0 + tx] = (__bf16)(f - (float)fh);
    }
}

__global__ __launch_bounds__(256) void transpose_bf16(const float* __restrict__ w,
                                                      __bf16* __restrict__ wt) {
    __shared__ float tile[32][33];
    int n0 = blockIdx.x * 32, k0 = blockIdx.y * 32;
    int tx = threadIdx.x & 31, ty = threadIdx.x >> 5;
#pragma unroll
    for (int i = 0; i < 32; i += 8)
        tile[ty + i][tx] = w[(k0 + ty + i) * DMODEL + n0 + tx];
    __syncthreads();
#pragma unroll
    for (int i = 0; i < 32; i += 8)
        wt[(n0 + ty + i) * DMODEL + k0 + tx] = (__bf16)tile[tx][ty + i];
}

// ---------------------------------------------------------------------------
// Split-bf16 GEMM (Q/K projections): C = Ahi.Bhi + Ahi.Blo + Alo.Bhi, fp32 acc.
// global_load_lds staging, unpadded [128][32] tiles (m97 pattern).
// Out: Q/K layout [((b*16+h)*2048+s)*64+d] as (hi, lo) bf16.
// ---------------------------------------------------------------------------
__global__ __launch_bounds__(256) void gemm_split(const __bf16* __restrict__ Ahi,
                                                  const __bf16* __restrict__ Alo,
                                                  const __bf16* __restrict__ Bthi,
                                                  const __bf16* __restrict__ Btlo,
                                                  __bf16* __restrict__ Ohi,
                                                  __bf16* __restrict__ Olo,
                                                  int M, int N, int K, float oscale) {
    __shared__ __bf16 Ash[128][32], Asl[128][32], Bsh[128][32], Bsl[128][32];
    int tid  = threadIdx.x;
    int wave = tid >> 6, lane = tid & 63;
    int quad = lane >> 4, l15 = lane & 15;
    int m0 = blockIdx.y * 128, n0 = blockIdx.x * 128;
    int wm = (wave >> 1) * 64, wn = (wave & 1) * 64;
    f32x4 acc[4][4] = {};

    int grow = (lane >> 2);            // row within 16-row wave chunk
    int gcol = (lane & 3) * 8;         // bf16 col within 32
    for (int k0 = 0; k0 < K; k0 += 32) {
        __syncthreads();
#pragma unroll
        for (int ps = 0; ps < 2; ps++) {
            int row = ps * 64 + wave * 16;
            gll16(&Ahi[(m0 + row + grow) * K + k0 + gcol], &Ash[row][0]);
            gll16(&Alo[(m0 + row + grow) * K + k0 + gcol], &Asl[row][0]);
            gll16(&Bthi[(n0 + row + grow) * K + k0 + gcol], &Bsh[row][0]);
            gll16(&Btlo[(n0 + row + grow) * K + k0 + gcol], &Bsl[row][0]);
        }
        __syncthreads();
        bf16x8 ah[4], al[4], bh[4], bl[4];
#pragma unroll
        for (int mi = 0; mi < 4; mi++) {
            ah[mi] = *(const bf16x8*)&Ash[wm + mi * 16 + l15][quad * 8];
            al[mi] = *(const bf16x8*)&Asl[wm + mi * 16 + l15][quad * 8];
        }
#pragma unroll
        for (int ni = 0; ni < 4; ni++) {
            bh[ni] = *(const bf16x8*)&Bsh[wn + ni * 16 + l15][quad * 8];
            bl[ni] = *(const bf16x8*)&Bsl[wn + ni * 16 + l15][quad * 8];
        }
#pragma unroll
        for (int mi = 0; mi < 4; mi++)
#pragma unroll
            for (int ni = 0; ni < 4; ni++) {
                acc[mi][ni] = __builtin_amdgcn_mfma_f32_16x16x32_bf16(ah[mi], bh[ni], acc[mi][ni], 0, 0, 0);
                acc[mi][ni] = __builtin_amdgcn_mfma_f32_16x16x32_bf16(ah[mi], bl[ni], acc[mi][ni], 0, 0, 0);
                acc[mi][ni] = __builtin_amdgcn_mfma_f32_16x16x32_bf16(al[mi], bh[ni], acc[mi][ni], 0, 0, 0);
            }
    }

#pragma unroll
    for (int mi = 0; mi < 4; mi++)
#pragma unroll
        for (int ni = 0; ni < 4; ni++)
#pragma unroll
            for (int rg = 0; rg < 4; rg++) {
                int m = m0 + wm + mi * 16 + quad * 4 + rg;
                int n = n0 + wn + ni * 16 + l15;
                float v = acc[mi][ni][rg] * oscale;
                int b = m >> 11, s = m & 2047;
                int h = n & 15,  d = n >> 4;
                size_t idx = ((size_t)(b * NHEADS + h) * S_LEN + s) * HDIM + d;
                __bf16 vh = (__bf16)v;
                Ohi[idx] = vh;
                Olo[idx] = (__bf16)(v - (float)vh);
            }
}

// ---------------------------------------------------------------------------
// Plain bf16 GEMM: MODE 0 fp32 row-major out; MODE 2 bf16 V^T layout.
// global_load_lds staging, unpadded tiles.
// ---------------------------------------------------------------------------
template <int MODE>
__global__ __launch_bounds__(256) void gemm_bt(const __bf16* __restrict__ A,
                                               const __bf16* __restrict__ Bt,
                                               void* __restrict__ outp,
                                               int M, int N, int K, float oscale) {
    __shared__ __bf16 As[128][32];
    __shared__ __bf16 Bs[128][32];
    int tid  = threadIdx.x;
    int wave = tid >> 6, lane = tid & 63;
    int quad = lane >> 4, l15 = lane & 15;
    int m0 = blockIdx.y * 128, n0 = blockIdx.x * 128;
    int wm = (wave >> 1) * 64, wn = (wave & 1) * 64;
    f32x4 acc[4][4] = {};

    int grow = (lane >> 2);
    int gcol = (lane & 3) * 8;
    for (int k0 = 0; k0 < K; k0 += 32) {
        __syncthreads();
#pragma unroll
        for (int ps = 0; ps < 2; ps++) {
            int row = ps * 64 + wave * 16;
            gll16(&A[(m0 + row + grow) * K + k0 + gcol], &As[row][0]);
            gll16(&Bt[(n0 + row + grow) * K + k0 + gcol], &Bs[row][0]);
        }
        __syncthreads();
        bf16x8 af[4], bfr[4];
#pragma unroll
        for (int mi = 0; mi < 4; mi++)
            af[mi] = *(const bf16x8*)&As[wm + mi * 16 + l15][quad * 8];
#pragma unroll
        for (int ni = 0; ni < 4; ni++)
            bfr[ni] = *(const bf16x8*)&Bs[wn + ni * 16 + l15][quad * 8];
#pragma unroll
        for (int mi = 0; mi < 4; mi++)
#pragma unroll
            for (int ni = 0; ni < 4; ni++)
                acc[mi][ni] = __builtin_amdgcn_mfma_f32_16x16x32_bf16(
                    af[mi], bfr[ni], acc[mi][ni], 0, 0, 0);
    }

#pragma unroll
    for (int mi = 0; mi < 4; mi++)
#pragma unroll
        for (int ni = 0; ni < 4; ni++)
#pragma unroll
            for (int rg = 0; rg < 4; rg++) {
                int m = m0 + wm + mi * 16 + quad * 4 + rg;
                int n = n0 + wn + ni * 16 + l15;
                float v = acc[mi][ni][rg] * oscale;
                if (MODE == 0) {
                    ((float*)outp)[(size_t)m * N + n] = v;
                } else {
                    int b = m >> 11, s = m & 2047;
                    int h = n & 15,  d = n >> 4;
                    ((__bf16*)outp)[((size_t)(b * NHEADS + h) * HDIM + d) * S_LEN + s] = (__bf16)v;
                }
            }
}

// ---------------------------------------------------------------------------
// Flash attention v3 — block-cooperative, LDS-staged K/V, causal.
// Block: 64-row q-tile pair (t1=p, t2=31-p) -> 33 kt-iters every block.
// K/V tile xor-swizzled in LDS (conflict-free b128 read/write).
// Reg-prefetch double buffer, one barrier per iter.
// ---------------------------------------------------------------------------
__global__ __launch_bounds__(256, 2) void flash_attn(const __bf16* __restrict__ Qhi,
                                                     const __bf16* __restrict__ Qlo,
                                                     const __bf16* __restrict__ Khi,
                                                     const __bf16* __restrict__ Klo,
                                                     const __bf16* __restrict__ Vt,
                                                     __bf16* __restrict__ attn) {
    // XCD swizzle: 512 blocks; xcd = id&7 gets heads {xcd, xcd+8, xcd+16, xcd+24}
    int id = blockIdx.x;
    int xcd = id & 7, which = id >> 3;       // which: 0..63
    int bh  = xcd + 8 * (which & 3);         // 0..31
    int p   = which >> 2;                    // pair 0..15
    int b = bh >> 4, h = bh & 15;
    const __bf16* Qhh = Qhi + (size_t)bh * S_LEN * HDIM;
    const __bf16* Qlh = Qlo + (size_t)bh * S_LEN * HDIM;
    const __bf16* Khh = Khi + (size_t)bh * S_LEN * HDIM;
    const __bf16* Klh = Klo + (size_t)bh * S_LEN * HDIM;
    const __bf16* Vh  = Vt  + (size_t)bh * HDIM * S_LEN;

    int tid = threadIdx.x, wave = tid >> 6, lane = tid & 63;
    int quad = lane >> 4, l15 = lane & 15;
    int t1 = p, t2 = 31 - p;
    int n1 = t1 + 1;                         // iters for tile1; total always 33

    // K/V LDS: Ks rows = key (0..63), 16 chunks of 16B: 0-7 hi, 8-15 lo,
    // chunk xor-swizzled by (key&7). Vs rows = dim, 8 chunks xor (dim&7).
    __shared__ __bf16 Ks[2][64][128];
    __shared__ __bf16 Vs[2][64][64];
    __shared__ __bf16 Ps[4][16][72];

    // Q fragments for both tiles (Q pre-scaled by 1/32)
    bf16x8 aqh0[2], aqh1[2], aql0[2], aql1[2];
#pragma unroll
    for (int tt = 0; tt < 2; tt++) {
        int q0 = (tt ? t2 : t1) * 64 + wave * 16;
        aqh0[tt] = *(const bf16x8*)&Qhh[(q0 + l15) * HDIM + quad * 8];
        aqh1[tt] = *(const bf16x8*)&Qhh[(q0 + l15) * HDIM + 32 + quad * 8];
        aql0[tt] = *(const bf16x8*)&Qlh[(q0 + l15) * HDIM + quad * 8];
        aql1[tt] = *(const bf16x8*)&Qlh[(q0 + l15) * HDIM + 32 + quad * 8];
    }

    // staging geometry: g in {tid, tid+256}; key/dim = g>>3, chunk = g&7
    int g1 = tid, g2 = tid + 256;
    int k1 = g1 >> 3, c1 = g1 & 7;
    int k2 = g2 >> 3, c2 = g2 & 7;
    uint4 pk0, pk1, pl0, pl1, pv0, pv1;

    // prefetch tile kt=0
    {
        int key0 = 0;
        pk0 = *(const uint4*)&Khh[(key0 + k1) * HDIM + c1 * 8];
        pk1 = *(const uint4*)&Khh[(key0 + k2) * HDIM + c2 * 8];
        pl0 = *(const uint4*)&Klh[(key0 + k1) * HDIM + c1 * 8];
        pl1 = *(const uint4*)&Klh[(key0 + k2) * HDIM + c2 * 8];
        pv0 = *(const uint4*)&Vh[(size_t)k1 * S_LEN + key0 + c1 * 8];
        pv1 = *(const uint4*)&Vh[(size_t)k2 * S_LEN + key0 + c2 * 8];
    }

    float m[4] = {-INFINITY, -INFINITY, -INFINITY, -INFINITY};
    float l[4] = {0.f, 0.f, 0.f, 0.f};
    f32x4 o[4] = {};
    int tsel = 0;
    int q0w  = t1 * 64 + wave * 16;

    for (int i = 0; i < 33; i++) {
        int kt   = (i < n1) ? i : i - n1;
        int key0 = kt * 64;
        int buf  = i & 1;

        // ---- stage prefetched regs -> LDS (xor-swizzled)
        *(uint4*)&Ks[buf][k1][((c1 ^ (k1 & 7))) * 8]      = pk0;
        *(uint4*)&Ks[buf][k2][((c2 ^ (k2 & 7))) * 8]      = pk1;
        *(uint4*)&Ks[buf][k1][(8 + (c1 ^ (k1 & 7))) * 8]  = pl0;
        *(uint4*)&Ks[buf][k2][(8 + (c2 ^ (k2 & 7))) * 8]  = pl1;
        *(uint4*)&Vs[buf][k1][(c1 ^ (k1 & 7)) * 8]        = pv0;
        *(uint4*)&Vs[buf][k2][(c2 ^ (k2 & 7)) * 8]        = pv1;
        __syncthreads();

        // ---- prefetch next tile (after barrier: not drained by it)
        if (i + 1 < 33) {
            int ktn   = (i + 1 < n1) ? i + 1 : i + 1 - n1;
            int key0n = ktn * 64;
            pk0 = *(const uint4*)&Khh[(key0n + k1) * HDIM + c1 * 8];
            pk1 = *(const uint4*)&Khh[(key0n + k2) * HDIM + c2 * 8];
            pl0 = *(const uint4*)&Klh[(key0n + k1) * HDIM + c1 * 8];
            pl1 = *(const uint4*)&Klh[(key0n + k2) * HDIM + c2 * 8];
            pv0 = *(const uint4*)&Vh[(size_t)k1 * S_LEN + key0n + c1 * 8];
            pv1 = *(const uint4*)&Vh[(size_t)k2 * S_LEN + key0n + c2 * 8];
        }

        // ---- S = (Q/32) K^T, split-bf16
        f32x4 sc[4] = {};
#pragma unroll
        for (int ni = 0; ni < 4; ni++) {
            int key = ni * 16 + l15;
            int sw  = key & 7;
            bf16x8 kh0 = *(const bf16x8*)&Ks[buf][key][((quad)     ^ sw) * 8];
            bf16x8 kh1 = *(const bf16x8*)&Ks[buf][key][((quad + 4) ^ sw) * 8];
            bf16x8 kl0 = *(const bf16x8*)&Ks[buf][key][(8 + ((quad)     ^ sw)) * 8];
            bf16x8 kl1 = *(const bf16x8*)&Ks[buf][key][(8 + ((quad + 4) ^ sw)) * 8];
            sc[ni] = __builtin_amdgcn_mfma_f32_16x16x32_bf16(aqh0[tsel], kh0, sc[ni], 0, 0, 0);
            sc[ni] = __builtin_amdgcn_mfma_f32_16x16x32_bf16(aqh1[tsel], kh1, sc[ni], 0, 0, 0);
            sc[ni] = __builtin_amdgcn_mfma_f32_16x16x32_bf16(aqh0[tsel], kl0, sc[ni], 0, 0, 0);
            sc[ni] = __builtin_amdgcn_mfma_f32_16x16x32_bf16(aqh1[tsel], kl1, sc[ni], 0, 0, 0);
            sc[ni] = __builtin_amdgcn_mfma_f32_16x16x32_bf16(aql0[tsel], kh0, sc[ni], 0, 0, 0);
            sc[ni] = __builtin_amdgcn_mfma_f32_16x16x32_bf16(aql1[tsel], kh1, sc[ni], 0, 0, 0);
        }

        // ---- causal mask + online softmax
        int qrow_base = q0w + quad * 4;
#pragma unroll
        for (int rg = 0; rg < 4; rg++) {
            int qrow = qrow_base + rg;
            float vals[4];
            float mx = -INFINITY;
#pragma unroll
            for (int ni = 0; ni < 4; ni++) {
                int key = key0 + ni * 16 + l15;
                float v = sc[ni][rg];
                if (key > qrow) v = -1e30f;
                vals[ni] = v;
                mx = fmaxf(mx, v);
            }
#pragma unroll
            for (int mm = 1; mm < 16; mm <<= 1)
                mx = fmaxf(mx, __shfl_xor(mx, mm, 64));
            float mnew  = fmaxf(m[rg], mx);
            float alpha = __expf(m[rg] - mnew);
            m[rg] = mnew;
            float rsum = 0.f;
#pragma unroll
            for (int ni = 0; ni < 4; ni++) {
                float px = __expf(vals[ni] - mnew);
                sc[ni][rg] = px;
                rsum += px;
            }
#pragma unroll
            for (int mm = 1; mm < 16; mm <<= 1)
                rsum += __shfl_xor(rsum, mm, 64);
            l[rg] = l[rg] * alpha + rsum;
#pragma unroll
            for (int ni = 0; ni < 4; ni++)
                o[ni][rg] *= alpha;
        }

        // ---- P: C-layout -> A-layout via wave-private LDS
#pragma unroll
        for (int ni = 0; ni < 4; ni++)
#pragma unroll
            for (int rg = 0; rg < 4; rg++)
                Ps[wave][quad * 4 + rg][ni * 16 + l15] = (__bf16)sc[ni][rg];

        // ---- O += P @ V  (V frags from swizzled LDS)
#pragma unroll
        for (int step = 0; step < 2; step++) {
            bf16x8 ap = *(const bf16x8*)&Ps[wave][l15][step * 32 + quad * 8];
#pragma unroll
            for (int ni = 0; ni < 4; ni++) {
                int dim = ni * 16 + l15;
                bf16x8 bv = *(const bf16x8*)&Vs[buf][dim][((step * 4 + quad) ^ (dim & 7)) * 8];
                o[ni] = __builtin_amdgcn_mfma_f32_16x16x32_bf16(ap, bv, o[ni], 0, 0, 0);
            }
        }

        // ---- tile boundaries: epilogue + reset
        if (i == n1 - 1 || i == 32) {
#pragma unroll
            for (int rg = 0; rg < 4; rg++) {
                float inv = 1.0f / l[rg];
                int q = q0w + quad * 4 + rg;
#pragma unroll
                for (int ni = 0; ni < 4; ni++) {
                    int d = ni * 16 + l15;
                    attn[((size_t)b * S_LEN + q) * DMODEL + d * NHEADS + h] =
                        (__bf16)(o[ni][rg] * inv);
                }
                m[rg] = -INFINITY;
                l[rg] = 0.f;
            }
#pragma unroll
            for (int ni = 0; ni < 4; ni++) o[ni] = (f32x4){0.f, 0.f, 0.f, 0.f};
            tsel = 1;
            q0w  = t2 * 64 + wave * 16;
        }
    }
}

// ---------------------------------------------------------------------------
extern "C" void kernel_launch(void* const* d_in, const int* in_sizes, int n_in,
                              void* d_out, int out_size, void* d_ws, size_t ws_size,
                              hipStream_t stream) {
    const float* x  = (const float*)d_in[0];
    const float* qw = (const float*)d_in[1];
    const float* kw = (const float*)d_in[2];
    const float* vw = (const float*)d_in[3];
    const float* ow = (const float*)d_in[4];

    char* ws = (char*)d_ws;
    const size_t MB = 1024 * 1024;
    __bf16* xhi   = (__bf16*)(ws);             //  8 MB  [4096,1024]
    __bf16* xlo   = (__bf16*)(ws + 8 * MB);    //  8 MB  (reused as attnb later)
    __bf16* qwthi = (__bf16*)(ws + 16 * MB);   //  2 MB each
    __bf16* qwtlo = (__bf16*)(ws + 18 * MB);
    __bf16* kwthi = (__bf16*)(ws + 20 * MB);
    __bf16* kwtlo = (__bf16*)(ws + 22 * MB);
    __bf16* vwt   = (__bf16*)(ws + 24 * MB);
    __bf16* owt   = (__bf16*)(ws + 26 * MB);
    __bf16* Qhi_b = (__bf16*)(ws + 28 * MB);   //  8 MB  [B,H,S,64]
    __bf16* Qlo_b = (__bf16*)(ws + 36 * MB);
    __bf16* Khi_b = (__bf16*)(ws + 44 * MB);
    __bf16* Klo_b = (__bf16*)(ws + 52 * MB);
    __bf16* Vtb   = (__bf16*)(ws + 60 * MB);   //  8 MB  [B,H,64,S]
    __bf16* attnb = xlo;                       //  alias: xlo dead after Q/K GEMMs

    conv_split<<<4096, 256, 0, stream>>>(x, xhi, xlo, 4096 * 1024 / 4);
    dim3 tg(32, 32);
    transpose_split<<<tg, 256, 0, stream>>>(qw, qwthi, qwtlo);
    transpose_split<<<tg, 256, 0, stream>>>(kw, kwthi, kwtlo);
    transpose_bf16<<<tg, 256, 0, stream>>>(vw, vwt);
    transpose_bf16<<<tg, 256, 0, stream>>>(ow, owt);

    dim3 gg(DMODEL / 128, 4096 / 128);  // (8, 32)
    gemm_split<<<gg, 256, 0, stream>>>(xhi, xlo, qwthi, qwtlo, Qhi_b, Qlo_b,
                                       4096, 1024, 1024, 0.03125f);
    gemm_split<<<gg, 256, 0, stream>>>(xhi, xlo, kwthi, kwtlo, Khi_b, Klo_b,
                                       4096, 1024, 1024, 1.0f);
    gemm_bt<2><<<gg, 256, 0, stream>>>(xhi, vwt, Vtb, 4096, 1024, 1024, 1.0f);

    flash_attn<<<512, 256, 0, stream>>>(Qhi_b, Qlo_b, Khi_b, Klo_b, Vtb, attnb);

    gemm_bt<0><<<gg, 256, 0, stream>>>(attnb, owt, d_out, 4096, 1024, 1024, 1.0f);
}

// Round 5
// 335.892 us; speedup vs baseline: 2.2359x; 1.2044x over previous
//
#include <hip/hip_runtime.h>

// ---------------------------------------------------------------------------
// MultiHeadAttention: B=2, S=2048, D=1024, H=16, hd=64
// Interleaved head split: Q[b,h,s,d] = proj[b,s, d*16+h]; scale = 1/32.
// Precision: split-bf16 (hi+lo) emulated-fp32 for Q/K path. V/attn/out plain bf16.
// Flash v4: block-cooperative, K/V staged in LDS in MFMA-FRAGMENT ORDER
// ([region][lane][8] -> lane-linear ds_read_b128, 2-way = free). Single
// buffer + register prefetch, 4 blocks/CU. Softmax in exp2 domain (log2e
// folded into Q scale); row-sum l computed by ones-MFMA (no sum butterfly);
// causal mask only on the diagonal tile. Pair (t, 31-t) -> 33 iters/block.
// ---------------------------------------------------------------------------

typedef __bf16 bf16x8 __attribute__((ext_vector_type(8)));
typedef __bf16 bf16x4 __attribute__((ext_vector_type(4)));
typedef float  f32x4  __attribute__((ext_vector_type(4)));

#define S_LEN  2048
#define DMODEL 1024
#define NHEADS 16
#define HDIM   64
#define LOG2E  1.44269504088896340736f

__device__ __forceinline__ void gll16(const __bf16* g, __bf16* l) {
    __builtin_amdgcn_global_load_lds(
        (const __attribute__((address_space(1))) unsigned int*)g,
        (__attribute__((address_space(3))) unsigned int*)l, 16, 0, 0);
}

// ---------------------------------------------------------------------------
// f32 -> (hi, lo) bf16 split, vectorized
// ---------------------------------------------------------------------------
__global__ __launch_bounds__(256) void conv_split(const float* __restrict__ x,
                                                  __bf16* __restrict__ hi,
                                                  __bf16* __restrict__ lo, int n4) {
    int i = blockIdx.x * 256 + threadIdx.x;
    if (i >= n4) return;
    float4 v = ((const float4*)x)[i];
    bf16x4 h, l;
#pragma unroll
    for (int c = 0; c < 4; c++) {
        float f = (&v.x)[c];
        __bf16 fh = (__bf16)f;
        h[c] = fh;
        l[c] = (__bf16)(f - (float)fh);
    }
    ((bf16x4*)hi)[i] = h;
    ((bf16x4*)lo)[i] = l;
}

// ---------------------------------------------------------------------------
// w[K][N] f32 -> wt[N][K] (hi, lo) split transpose
// ---------------------------------------------------------------------------
__global__ __launch_bounds__(256) void transpose_split(const float* __restrict__ w,
                                                       __bf16* __restrict__ wthi,
                                                       __bf16* __restrict__ wtlo) {
    __shared__ float tile[32][33];
    int n0 = blockIdx.x * 32, k0 = blockIdx.y * 32;
    int tx = threadIdx.x & 31, ty = threadIdx.x >> 5;
#pragma unroll
    for (int i = 0; i < 32; i += 8)
        tile[ty + i][tx] = w[(k0 + ty + i) * DMODEL + n0 + tx];
    __syncthreads();
#pragma unroll
    for (int i = 0; i < 32; i += 8) {
        float f = tile[tx][ty + i];
        __bf16 fh = (__bf16)f;
        wthi[(n0 + ty + i) * DMODEL + k0 + tx] = fh;
        wtlo[(n0 + ty + i) * DMODEL + k0 + tx] = (__bf16)(f - (float)fh);
    }
}

__global__ __launch_bounds__(256) void transpose_bf16(const float* __restrict__ w,
                                                      __bf16* __restrict__ wt) {
    __shared__ float tile[32][33];
    int n0 = blockIdx.x * 32, k0 = blockIdx.y * 32;
    int tx = threadIdx.x & 31, ty = threadIdx.x >> 5;
#pragma unroll
    for (int i = 0; i < 32; i += 8)
        tile[ty + i][tx] = w[(k0 + ty + i) * DMODEL + n0 + tx];
    __syncthreads();
#pragma unroll
    for (int i = 0; i < 32; i += 8)
        wt[(n0 + ty + i) * DMODEL + k0 + tx] = (__bf16)tile[tx][ty + i];
}

// ---------------------------------------------------------------------------
// Split-bf16 GEMM (Q/K projections): C = Ahi.Bhi + Ahi.Blo + Alo.Bhi, fp32 acc.
// ---------------------------------------------------------------------------
__global__ __launch_bounds__(256) void gemm_split(const __bf16* __restrict__ Ahi,
                                                  const __bf16* __restrict__ Alo,
                                                  const __bf16* __restrict__ Bthi,
                                                  const __bf16* __restrict__ Btlo,
                                                  __bf16* __restrict__ Ohi,
                                                  __bf16* __restrict__ Olo,
                                                  int M, int N, int K, float oscale) {
    __shared__ __bf16 Ash[128][32], Asl[128][32], Bsh[128][32], Bsl[128][32];
    int tid  = threadIdx.x;
    int wave = tid >> 6, lane = tid & 63;
    int quad = lane >> 4, l15 = lane & 15;
    int m0 = blockIdx.y * 128, n0 = blockIdx.x * 128;
    int wm = (wave >> 1) * 64, wn = (wave & 1) * 64;
    f32x4 acc[4][4] = {};

    int grow = (lane >> 2);
    int gcol = (lane & 3) * 8;
    for (int k0 = 0; k0 < K; k0 += 32) {
        __syncthreads();
#pragma unroll
        for (int ps = 0; ps < 2; ps++) {
            int row = ps * 64 + wave * 16;
            gll16(&Ahi[(m0 + row + grow) * K + k0 + gcol], &Ash[row][0]);
            gll16(&Alo[(m0 + row + grow) * K + k0 + gcol], &Asl[row][0]);
            gll16(&Bthi[(n0 + row + grow) * K + k0 + gcol], &Bsh[row][0]);
            gll16(&Btlo[(n0 + row + grow) * K + k0 + gcol], &Bsl[row][0]);
        }
        __syncthreads();
        bf16x8 ah[4], al[4], bh[4], bl[4];
#pragma unroll
        for (int mi = 0; mi < 4; mi++) {
            ah[mi] = *(const bf16x8*)&Ash[wm + mi * 16 + l15][quad * 8];
            al[mi] = *(const bf16x8*)&Asl[wm + mi * 16 + l15][quad * 8];
        }
#pragma unroll
        for (int ni = 0; ni < 4; ni++) {
            bh[ni] = *(const bf16x8*)&Bsh[wn + ni * 16 + l15][quad * 8];
            bl[ni] = *(const bf16x8*)&Bsl[wn + ni * 16 + l15][quad * 8];
        }
#pragma unroll
        for (int mi = 0; mi < 4; mi++)
#pragma unroll
            for (int ni = 0; ni < 4; ni++) {
                acc[mi][ni] = __builtin_amdgcn_mfma_f32_16x16x32_bf16(ah[mi], bh[ni], acc[mi][ni], 0, 0, 0);
                acc[mi][ni] = __builtin_amdgcn_mfma_f32_16x16x32_bf16(ah[mi], bl[ni], acc[mi][ni], 0, 0, 0);
                acc[mi][ni] = __builtin_amdgcn_mfma_f32_16x16x32_bf16(al[mi], bh[ni], acc[mi][ni], 0, 0, 0);
            }
    }

#pragma unroll
    for (int mi = 0; mi < 4; mi++)
#pragma unroll
        for (int ni = 0; ni < 4; ni++)
#pragma unroll
            for (int rg = 0; rg < 4; rg++) {
                int m = m0 + wm + mi * 16 + quad * 4 + rg;
                int n = n0 + wn + ni * 16 + l15;
                float v = acc[mi][ni][rg] * oscale;
                int b = m >> 11, s = m & 2047;
                int h = n & 15,  d = n >> 4;
                size_t idx = ((size_t)(b * NHEADS + h) * S_LEN + s) * HDIM + d;
                __bf16 vh = (__bf16)v;
                Ohi[idx] = vh;
                Olo[idx] = (__bf16)(v - (float)vh);
            }
}

// ---------------------------------------------------------------------------
// Plain bf16 GEMM: MODE 0 fp32 row-major out; MODE 2 bf16 V^T layout.
// ---------------------------------------------------------------------------
template <int MODE>
__global__ __launch_bounds__(256) void gemm_bt(const __bf16* __restrict__ A,
                                               const __bf16* __restrict__ Bt,
                                               void* __restrict__ outp,
                                               int M, int N, int K, float oscale) {
    __shared__ __bf16 As[128][32];
    __shared__ __bf16 Bs[128][32];
    int tid  = threadIdx.x;
    int wave = tid >> 6, lane = tid & 63;
    int quad = lane >> 4, l15 = lane & 15;
    int m0 = blockIdx.y * 128, n0 = blockIdx.x * 128;
    int wm = (wave >> 1) * 64, wn = (wave & 1) * 64;
    f32x4 acc[4][4] = {};

    int grow = (lane >> 2);
    int gcol = (lane & 3) * 8;
    for (int k0 = 0; k0 < K; k0 += 32) {
        __syncthreads();
#pragma unroll
        for (int ps = 0; ps < 2; ps++) {
            int row = ps * 64 + wave * 16;
            gll16(&A[(m0 + row + grow) * K + k0 + gcol], &As[row][0]);
            gll16(&Bt[(n0 + row + grow) * K + k0 + gcol], &Bs[row][0]);
        }
        __syncthreads();
        bf16x8 af[4], bfr[4];
#pragma unroll
        for (int mi = 0; mi < 4; mi++)
            af[mi] = *(const bf16x8*)&As[wm + mi * 16 + l15][quad * 8];
#pragma unroll
        for (int ni = 0; ni < 4; ni++)
            bfr[ni] = *(const bf16x8*)&Bs[wn + ni * 16 + l15][quad * 8];
#pragma unroll
        for (int mi = 0; mi < 4; mi++)
#pragma unroll
            for (int ni = 0; ni < 4; ni++)
                acc[mi][ni] = __builtin_amdgcn_mfma_f32_16x16x32_bf16(
                    af[mi], bfr[ni], acc[mi][ni], 0, 0, 0);
    }

#pragma unroll
    for (int mi = 0; mi < 4; mi++)
#pragma unroll
        for (int ni = 0; ni < 4; ni++)
#pragma unroll
            for (int rg = 0; rg < 4; rg++) {
                int m = m0 + wm + mi * 16 + quad * 4 + rg;
                int n = n0 + wn + ni * 16 + l15;
                float v = acc[mi][ni][rg] * oscale;
                if (MODE == 0) {
                    ((float*)outp)[(size_t)m * N + n] = v;
                } else {
                    int b = m >> 11, s = m & 2047;
                    int h = n & 15,  d = n >> 4;
                    ((__bf16*)outp)[((size_t)(b * NHEADS + h) * HDIM + d) * S_LEN + s] = (__bf16)v;
                }
            }
}

// ---------------------------------------------------------------------------
// Flash attention v4. Q pre-scaled by log2e/32 (exp2-domain softmax).
// LDS: K/V in fragment order [region][lane][8] -> lane-linear b128 (2-way).
// ---------------------------------------------------------------------------
__global__ __launch_bounds__(256, 4) void flash_attn(const __bf16* __restrict__ Qhi,
                                                     const __bf16* __restrict__ Qlo,
                                                     const __bf16* __restrict__ Khi,
                                                     const __bf16* __restrict__ Klo,
                                                     const __bf16* __restrict__ Vt,
                                                     __bf16* __restrict__ attn) {
    // XCD swizzle: 512 blocks; xcd = id&7 gets heads {xcd, xcd+8, xcd+16, xcd+24}
    int id = blockIdx.x;
    int xcd = id & 7, which = id >> 3;
    int bh  = xcd + 8 * (which & 3);
    int p   = which >> 2;
    int b = bh >> 4, h = bh & 15;
    const __bf16* Qhh = Qhi + (size_t)bh * S_LEN * HDIM;
    const __bf16* Qlh = Qlo + (size_t)bh * S_LEN * HDIM;
    const __bf16* Khh = Khi + (size_t)bh * S_LEN * HDIM;
    const __bf16* Klh = Klo + (size_t)bh * S_LEN * HDIM;
    const __bf16* Vh  = Vt  + (size_t)bh * HDIM * S_LEN;

    int tid = threadIdx.x, wave = tid >> 6, lane = tid & 63;
    int quad = lane >> 4, l15 = lane & 15;
    int t1 = p, t2 = 31 - p;
    int n1 = t1 + 1;                       // iters for tile1; total always 33

    // K/V in fragment order: [8 regions][64 lanes][8 el]. 8 KB each.
    __shared__ __bf16 KhF[8 * 64 * 8];
    __shared__ __bf16 KlF[8 * 64 * 8];
    __shared__ __bf16 VF [8 * 64 * 8];
    __shared__ __bf16 Ps[4][16][72];

    // staging geometry: c = tid>>6 (0..3, +4 for 2nd load), key/dim = tid&63
    int c1  = tid >> 6, key = tid & 63;
    int inner = (c1 * 16 + (key & 15)) * 8;
    int rK    = (key >> 4);
    int kdst0 = rK * 512 + inner, kdst1 = (4 + rK) * 512 + inner;
    const __bf16* vrow = Vh + (size_t)key * S_LEN;   // dim = key var

    // Q frags for tile1 (Q pre-scaled by log2e/32)
    int q0w = t1 * 64 + wave * 16;
    bf16x8 aqh0 = *(const bf16x8*)&Qhh[(q0w + l15) * HDIM + quad * 8];
    bf16x8 aqh1 = *(const bf16x8*)&Qhh[(q0w + l15) * HDIM + 32 + quad * 8];
    bf16x8 aql0 = *(const bf16x8*)&Qlh[(q0w + l15) * HDIM + quad * 8];
    bf16x8 aql1 = *(const bf16x8*)&Qlh[(q0w + l15) * HDIM + 32 + quad * 8];

    bf16x8 ones;
#pragma unroll
    for (int j = 0; j < 8; j++) ones[j] = (__bf16)1.0f;

    uint4 pk0, pk1, pl0, pl1, pv0, pv1;
    {   // prefetch tile kt=0
        const __bf16* sk = Khh + key * HDIM;
        const __bf16* sl = Klh + key * HDIM;
        pk0 = *(const uint4*)(sk + c1 * 8); pk1 = *(const uint4*)(sk + c1 * 8 + 32);
        pl0 = *(const uint4*)(sl + c1 * 8); pl1 = *(const uint4*)(sl + c1 * 8 + 32);
        pv0 = *(const uint4*)(vrow + c1 * 8); pv1 = *(const uint4*)(vrow + c1 * 8 + 32);
    }

    float m[4] = {-3e38f, -3e38f, -3e38f, -3e38f};
    f32x4 o[4] = {};
    f32x4 ol = {};
    int qrb = q0w + quad * 4;

    for (int i = 0; i < 33; i++) {
        int kt   = (i < n1) ? i : i - n1;
        int key0 = kt * 64;
        bool diag = (i == n1 - 1) || (i == 32);

        __syncthreads();   // previous compute done reading LDS
        *(uint4*)&KhF[kdst0] = pk0;  *(uint4*)&KhF[kdst1] = pk1;
        *(uint4*)&KlF[kdst0] = pl0;  *(uint4*)&KlF[kdst1] = pl1;
        *(uint4*)&VF [kdst0] = pv0;  *(uint4*)&VF [kdst1] = pv1;
        __syncthreads();   // LDS ready

        // prefetch next tile into regs (lands during compute)
        if (i + 1 < 33) {
            int ktn   = (i + 1 < n1) ? i + 1 : i + 1 - n1;
            int key0n = ktn * 64;
            const __bf16* sk = Khh + (key0n + key) * HDIM;
            const __bf16* sl = Klh + (key0n + key) * HDIM;
            pk0 = *(const uint4*)(sk + c1 * 8); pk1 = *(const uint4*)(sk + c1 * 8 + 32);
            pl0 = *(const uint4*)(sl + c1 * 8); pl1 = *(const uint4*)(sl + c1 * 8 + 32);
            pv0 = *(const uint4*)(vrow + key0n + c1 * 8);
            pv1 = *(const uint4*)(vrow + key0n + c1 * 8 + 32);
        }

        // ---- S(log2 domain) = Q K^T, split-bf16: hi.hi + hi.lo + lo.hi
        f32x4 sc[4] = {};
#pragma unroll
        for (int ni = 0; ni < 4; ni++) {
            bf16x8 kh0 = *(const bf16x8*)&KhF[(ni * 64 + lane) * 8];
            bf16x8 kh1 = *(const bf16x8*)&KhF[((4 + ni) * 64 + lane) * 8];
            bf16x8 kl0 = *(const bf16x8*)&KlF[(ni * 64 + lane) * 8];
            bf16x8 kl1 = *(const bf16x8*)&KlF[((4 + ni) * 64 + lane) * 8];
            sc[ni] = __builtin_amdgcn_mfma_f32_16x16x32_bf16(aqh0, kh0, sc[ni], 0, 0, 0);
            sc[ni] = __builtin_amdgcn_mfma_f32_16x16x32_bf16(aqh1, kh1, sc[ni], 0, 0, 0);
            sc[ni] = __builtin_amdgcn_mfma_f32_16x16x32_bf16(aqh0, kl0, sc[ni], 0, 0, 0);
            sc[ni] = __builtin_amdgcn_mfma_f32_16x16x32_bf16(aqh1, kl1, sc[ni], 0, 0, 0);
            sc[ni] = __builtin_amdgcn_mfma_f32_16x16x32_bf16(aql0, kh0, sc[ni], 0, 0, 0);
            sc[ni] = __builtin_amdgcn_mfma_f32_16x16x32_bf16(aql1, kh1, sc[ni], 0, 0, 0);
        }

        // ---- causal mask: only the diagonal tile needs it
        if (diag) {
#pragma unroll
            for (int ni = 0; ni < 4; ni++) {
                int keyi = key0 + ni * 16 + l15;
#pragma unroll
                for (int rg = 0; rg < 4; rg++)
                    if (keyi > qrb + rg) sc[ni][rg] = -1e30f;
            }
        }

        // ---- online softmax: max butterfly only (l comes from ones-MFMA)
#pragma unroll
        for (int rg = 0; rg < 4; rg++) {
            float mx = fmaxf(fmaxf(sc[0][rg], sc[1][rg]),
                             fmaxf(sc[2][rg], sc[3][rg]));
#pragma unroll
            for (int mm = 1; mm < 16; mm <<= 1)
                mx = fmaxf(mx, __shfl_xor(mx, mm, 64));
            float mnew  = fmaxf(m[rg], mx);
            float alpha = __builtin_amdgcn_exp2f(m[rg] - mnew);
            m[rg] = mnew;
#pragma unroll
            for (int ni = 0; ni < 4; ni++) {
                float px = __builtin_amdgcn_exp2f(sc[ni][rg] - mnew);
                Ps[wave][quad * 4 + rg][ni * 16 + l15] = (__bf16)px;
            }
            ol[rg] *= alpha;
#pragma unroll
            for (int ni = 0; ni < 4; ni++)
                o[ni][rg] *= alpha;
        }

        // ---- O += P @ V ; l += P @ 1  (fragment-order V reads)
#pragma unroll
        for (int step = 0; step < 2; step++) {
            bf16x8 ap = *(const bf16x8*)&Ps[wave][l15][step * 32 + quad * 8];
            ol = __builtin_amdgcn_mfma_f32_16x16x32_bf16(ap, ones, ol, 0, 0, 0);
#pragma unroll
            for (int ni = 0; ni < 4; ni++) {
                bf16x8 bv = *(const bf16x8*)&VF[((step * 4 + ni) * 64 + lane) * 8];
                o[ni] = __builtin_amdgcn_mfma_f32_16x16x32_bf16(ap, bv, o[ni], 0, 0, 0);
            }
        }

        // ---- tile boundary: epilogue + reset (+ Q frag reload for tile2)
        if (diag) {
#pragma unroll
            for (int rg = 0; rg < 4; rg++) {
                float inv = 1.0f / ol[rg];
                int q = q0w + quad * 4 + rg;
#pragma unroll
                for (int ni = 0; ni < 4; ni++) {
                    int d = ni * 16 + l15;
                    attn[((size_t)b * S_LEN + q) * DMODEL + d * NHEADS + h] =
                        (__bf16)(o[ni][rg] * inv);
                }
                m[rg] = -3e38f;
            }
#pragma unroll
            for (int ni = 0; ni < 4; ni++) o[ni] = (f32x4){0.f, 0.f, 0.f, 0.f};
            ol = (f32x4){0.f, 0.f, 0.f, 0.f};
            if (i == n1 - 1) {
                q0w = t2 * 64 + wave * 16;
                qrb = q0w + quad * 4;
                aqh0 = *(const bf16x8*)&Qhh[(q0w + l15) * HDIM + quad * 8];
                aqh1 = *(const bf16x8*)&Qhh[(q0w + l15) * HDIM + 32 + quad * 8];
                aql0 = *(const bf16x8*)&Qlh[(q0w + l15) * HDIM + quad * 8];
                aql1 = *(const bf16x8*)&Qlh[(q0w + l15) * HDIM + 32 + quad * 8];
            }
        }
    }
}

// ---------------------------------------------------------------------------
extern "C" void kernel_launch(void* const* d_in, const int* in_sizes, int n_in,
                              void* d_out, int out_size, void* d_ws, size_t ws_size,
                              hipStream_t stream) {
    const float* x  = (const float*)d_in[0];
    const float* qw = (const float*)d_in[1];
    const float* kw = (const float*)d_in[2];
    const float* vw = (const float*)d_in[3];
    const float* ow = (const float*)d_in[4];

    char* ws = (char*)d_ws;
    const size_t MB = 1024 * 1024;
    __bf16* xhi   = (__bf16*)(ws);             //  8 MB  [4096,1024]
    __bf16* xlo   = (__bf16*)(ws + 8 * MB);    //  8 MB  (reused as attnb later)
    __bf16* qwthi = (__bf16*)(ws + 16 * MB);   //  2 MB each
    __bf16* qwtlo = (__bf16*)(ws + 18 * MB);
    __bf16* kwthi = (__bf16*)(ws + 20 * MB);
    __bf16* kwtlo = (__bf16*)(ws + 22 * MB);
    __bf16* vwt   = (__bf16*)(ws + 24 * MB);
    __bf16* owt   = (__bf16*)(ws + 26 * MB);
    __bf16* Qhi_b = (__bf16*)(ws + 28 * MB);   //  8 MB  [B,H,S,64]
    __bf16* Qlo_b = (__bf16*)(ws + 36 * MB);
    __bf16* Khi_b = (__bf16*)(ws + 44 * MB);
    __bf16* Klo_b = (__bf16*)(ws + 52 * MB);
    __bf16* Vtb   = (__bf16*)(ws + 60 * MB);   //  8 MB  [B,H,64,S]
    __bf16* attnb = xlo;                       //  alias: xlo dead after Q/K GEMMs

    conv_split<<<4096, 256, 0, stream>>>(x, xhi, xlo, 4096 * 1024 / 4);
    dim3 tg(32, 32);
    transpose_split<<<tg, 256, 0, stream>>>(qw, qwthi, qwtlo);
    transpose_split<<<tg, 256, 0, stream>>>(kw, kwthi, kwtlo);
    transpose_bf16<<<tg, 256, 0, stream>>>(vw, vwt);
    transpose_bf16<<<tg, 256, 0, stream>>>(ow, owt);

    dim3 gg(DMODEL / 128, 4096 / 128);  // (8, 32)
    // Q scaled by log2e/32: softmax runs in exp2 domain
    gemm_split<<<gg, 256, 0, stream>>>(xhi, xlo, qwthi, qwtlo, Qhi_b, Qlo_b,
                                       4096, 1024, 1024, 0.03125f * LOG2E);
    gemm_split<<<gg, 256, 0, stream>>>(xhi, xlo, kwthi, kwtlo, Khi_b, Klo_b,
                                       4096, 1024, 1024, 1.0f);
    gemm_bt<2><<<gg, 256, 0, stream>>>(xhi, vwt, Vtb, 4096, 1024, 1024, 1.0f);

    flash_attn<<<512, 256, 0, stream>>>(Qhi_b, Qlo_b, Khi_b, Klo_b, Vtb, attnb);

    gemm_bt<0><<<gg, 256, 0, stream>>>(attnb, owt, d_out, 4096, 1024, 1024, 1.0f);
}

// Round 6
// 254.460 us; speedup vs baseline: 2.9514x; 1.3200x over previous
//
#include <hip/hip_runtime.h>

// ---------------------------------------------------------------------------
// MultiHeadAttention: B=2, S=2048, D=1024, H=16, hd=64
// Interleaved head split: Q[b,h,s,d] = proj[b,s, d*16+h]; scale = 1/32.
// Precision: split-bf16 (hi+lo) emulated-fp32 for Q/K path. V/attn/out plain bf16.
// v5: merged layouts everywhere. Weight transposes permute columns so that
// Q/K/attn are stored [b*2048+s][h*64+d] (coalesced epilogues + flash writes).
// QKV projections fused into one kernel (grid z: 0=Q split, 1=K split,
// 2=V computed transposed -> [bh][d][s]). Out-proj reads attnb with
// row-permuted owt. Flash: v4 structure (frag-order LDS, exp2 softmax,
// ones-MFMA row-sum, diag-only mask, pair(t,31-t) balance).
// ---------------------------------------------------------------------------

typedef __bf16 bf16x8 __attribute__((ext_vector_type(8)));
typedef __bf16 bf16x4 __attribute__((ext_vector_type(4)));
typedef float  f32x4  __attribute__((ext_vector_type(4)));

#define S_LEN  2048
#define DMODEL 1024
#define NHEADS 16
#define HDIM   64
#define LOG2E  1.44269504088896340736f

__device__ __forceinline__ void gll16(const __bf16* g, __bf16* l) {
    __builtin_amdgcn_global_load_lds(
        (const __attribute__((address_space(1))) unsigned int*)g,
        (__attribute__((address_space(3))) unsigned int*)l, 16, 0, 0);
}

// ---------------------------------------------------------------------------
// f32 -> (hi, lo) bf16 split, vectorized
// ---------------------------------------------------------------------------
__global__ __launch_bounds__(256) void conv_split(const float* __restrict__ x,
                                                  __bf16* __restrict__ hi,
                                                  __bf16* __restrict__ lo, int n4) {
    int i = blockIdx.x * 256 + threadIdx.x;
    if (i >= n4) return;
    float4 v = ((const float4*)x)[i];
    bf16x4 h, l;
#pragma unroll
    for (int c = 0; c < 4; c++) {
        float f = (&v.x)[c];
        __bf16 fh = (__bf16)f;
        h[c] = fh;
        l[c] = (__bf16)(f - (float)fh);
    }
    ((bf16x4*)hi)[i] = h;
    ((bf16x4*)lo)[i] = l;
}

// ---------------------------------------------------------------------------
// Fused weight transposes. z=0: qw -> split, col-permuted (row c=perm(n)).
// z=1: kw likewise. z=2: vw plain wt[n][k]. z=3: ow plain, k-permuted
// (owt[n][perm(k)]), matching attnb's merged channel c=h*64+d.
// perm(i) = (i&15)*64 + (i>>4).
// ---------------------------------------------------------------------------
__global__ __launch_bounds__(256) void transpose_all(
    const float* __restrict__ qw, const float* __restrict__ kw,
    const float* __restrict__ vw, const float* __restrict__ ow,
    __bf16* __restrict__ qwthi, __bf16* __restrict__ qwtlo,
    __bf16* __restrict__ kwthi, __bf16* __restrict__ kwtlo,
    __bf16* __restrict__ vwt,  __bf16* __restrict__ owt) {
    __shared__ float tile[32][33];
    int z = blockIdx.z;
    const float* w = (z == 0) ? qw : (z == 1) ? kw : (z == 2) ? vw : ow;
    int n0 = blockIdx.x * 32, k0 = blockIdx.y * 32;
    int tx = threadIdx.x & 31, ty = threadIdx.x >> 5;
#pragma unroll
    for (int i = 0; i < 32; i += 8)
        tile[ty + i][tx] = w[(k0 + ty + i) * DMODEL + n0 + tx];
    __syncthreads();
#pragma unroll
    for (int i = 0; i < 32; i += 8) {
        float f = tile[tx][ty + i];           // = w[k0+tx][n0+ty+i]
        int k = k0 + tx, n = n0 + ty + i;
        if (z <= 1) {
            __bf16 fh = (__bf16)f;
            __bf16 fl = (__bf16)(f - (float)fh);
            int c = (n & 15) * 64 + (n >> 4);
            if (z == 0) { qwthi[c * DMODEL + k] = fh; qwtlo[c * DMODEL + k] = fl; }
            else        { kwthi[c * DMODEL + k] = fh; kwtlo[c * DMODEL + k] = fl; }
        } else if (z == 2) {
            vwt[n * DMODEL + k] = (__bf16)f;
        } else {
            int ck = (k & 15) * 64 + (k >> 4);
            owt[n * DMODEL + ck] = (__bf16)f;
        }
    }
}

// ---------------------------------------------------------------------------
// Fused QKV projection GEMM. grid (8, 32, 3).
// z=0: Q = x @ qw (split-bf16, scale log2e/32), merged [m][c] hi/lo out.
// z=1: K likewise, scale 1.
// z=2: V^T = vwt @ x^T (plain), out [bh][d][s] (32B-coalesced segments).
// ---------------------------------------------------------------------------
__global__ __launch_bounds__(256) void qkv_gemm(
    const __bf16* __restrict__ xhi, const __bf16* __restrict__ xlo,
    const __bf16* __restrict__ qwthi, const __bf16* __restrict__ qwtlo,
    const __bf16* __restrict__ kwthi, const __bf16* __restrict__ kwtlo,
    const __bf16* __restrict__ vwt,
    __bf16* __restrict__ Qhi, __bf16* __restrict__ Qlo,
    __bf16* __restrict__ Khi, __bf16* __restrict__ Klo,
    __bf16* __restrict__ Vt) {
    __shared__ __bf16 Ash[128][32], Asl[128][32], Bsh[128][32], Bsl[128][32];
    int mode = blockIdx.z;
    int tid  = threadIdx.x;
    int wave = tid >> 6, lane = tid & 63;
    int quad = lane >> 4, l15 = lane & 15;
    int wm = (wave >> 1) * 64, wn = (wave & 1) * 64;
    int grow = lane >> 2, gcol = (lane & 3) * 8;
    const int K = DMODEL;

    if (mode < 2) {
        const __bf16* Bh = mode ? kwthi : qwthi;
        const __bf16* Bl = mode ? kwtlo : qwtlo;
        int m0 = blockIdx.y * 128, n0 = blockIdx.x * 128;
        f32x4 acc[4][4] = {};
        for (int k0 = 0; k0 < K; k0 += 32) {
            __syncthreads();
#pragma unroll
            for (int ps = 0; ps < 2; ps++) {
                int row = ps * 64 + wave * 16;
                gll16(&xhi[(m0 + row + grow) * K + k0 + gcol], &Ash[row][0]);
                gll16(&xlo[(m0 + row + grow) * K + k0 + gcol], &Asl[row][0]);
                gll16(&Bh [(n0 + row + grow) * K + k0 + gcol], &Bsh[row][0]);
                gll16(&Bl [(n0 + row + grow) * K + k0 + gcol], &Bsl[row][0]);
            }
            __syncthreads();
            bf16x8 ah[4], al[4], bh[4], bl[4];
#pragma unroll
            for (int mi = 0; mi < 4; mi++) {
                ah[mi] = *(const bf16x8*)&Ash[wm + mi * 16 + l15][quad * 8];
                al[mi] = *(const bf16x8*)&Asl[wm + mi * 16 + l15][quad * 8];
            }
#pragma unroll
            for (int ni = 0; ni < 4; ni++) {
                bh[ni] = *(const bf16x8*)&Bsh[wn + ni * 16 + l15][quad * 8];
                bl[ni] = *(const bf16x8*)&Bsl[wn + ni * 16 + l15][quad * 8];
            }
#pragma unroll
            for (int mi = 0; mi < 4; mi++)
#pragma unroll
                for (int ni = 0; ni < 4; ni++) {
                    acc[mi][ni] = __builtin_amdgcn_mfma_f32_16x16x32_bf16(ah[mi], bh[ni], acc[mi][ni], 0, 0, 0);
                    acc[mi][ni] = __builtin_amdgcn_mfma_f32_16x16x32_bf16(ah[mi], bl[ni], acc[mi][ni], 0, 0, 0);
                    acc[mi][ni] = __builtin_amdgcn_mfma_f32_16x16x32_bf16(al[mi], bh[ni], acc[mi][ni], 0, 0, 0);
                }
        }
        float oscale = mode ? 1.0f : 0.03125f * LOG2E;
        __bf16* Ohi = mode ? Khi : Qhi;
        __bf16* Olo = mode ? Klo : Qlo;
#pragma unroll
        for (int mi = 0; mi < 4; mi++)
#pragma unroll
            for (int ni = 0; ni < 4; ni++)
#pragma unroll
                for (int rg = 0; rg < 4; rg++) {
                    int m = m0 + wm + mi * 16 + quad * 4 + rg;
                    int n = n0 + wn + ni * 16 + l15;     // n == merged channel
                    float v = acc[mi][ni][rg] * oscale;
                    size_t idx = (size_t)m * DMODEL + n;
                    __bf16 vh = (__bf16)v;
                    Ohi[idx] = vh;
                    Olo[idx] = (__bf16)(v - (float)vh);
                }
    } else {
        // V^T: A = vwt (channel rows), B = xhi (x rows); C[ch][xm]
        int ch0 = blockIdx.x * 128, xm0 = blockIdx.y * 128;
        f32x4 acc[4][4] = {};
        for (int k0 = 0; k0 < K; k0 += 32) {
            __syncthreads();
#pragma unroll
            for (int ps = 0; ps < 2; ps++) {
                int row = ps * 64 + wave * 16;
                gll16(&vwt[(ch0 + row + grow) * K + k0 + gcol], &Ash[row][0]);
                gll16(&xhi[(xm0 + row + grow) * K + k0 + gcol], &Bsh[row][0]);
            }
            __syncthreads();
            bf16x8 af[4], bfr[4];
#pragma unroll
            for (int mi = 0; mi < 4; mi++)
                af[mi] = *(const bf16x8*)&Ash[wm + mi * 16 + l15][quad * 8];
#pragma unroll
            for (int ni = 0; ni < 4; ni++)
                bfr[ni] = *(const bf16x8*)&Bsh[wn + ni * 16 + l15][quad * 8];
#pragma unroll
            for (int mi = 0; mi < 4; mi++)
#pragma unroll
                for (int ni = 0; ni < 4; ni++)
                    acc[mi][ni] = __builtin_amdgcn_mfma_f32_16x16x32_bf16(
                        af[mi], bfr[ni], acc[mi][ni], 0, 0, 0);
        }
#pragma unroll
        for (int mi = 0; mi < 4; mi++)
#pragma unroll
            for (int ni = 0; ni < 4; ni++)
#pragma unroll
                for (int rg = 0; rg < 4; rg++) {
                    int ch = ch0 + wm + mi * 16 + quad * 4 + rg;
                    int xm = xm0 + wn + ni * 16 + l15;
                    int b = xm >> 11, s = xm & 2047;
                    int h = ch & 15,  d = ch >> 4;
                    Vt[((size_t)(b * NHEADS + h) * HDIM + d) * S_LEN + s] =
                        (__bf16)acc[mi][ni][rg];
                }
    }
}

// ---------------------------------------------------------------------------
// Output projection: out[m][n] = attnb[m][:] . owt[n][:], fp32 out.
// 64x128 tiles -> grid (8,64) = 512 blocks (2/CU).
// ---------------------------------------------------------------------------
__global__ __launch_bounds__(256) void out_gemm(const __bf16* __restrict__ A,
                                                const __bf16* __restrict__ Bt,
                                                float* __restrict__ out) {
    __shared__ __bf16 As[64][32];
    __shared__ __bf16 Bs[128][32];
    int tid  = threadIdx.x;
    int wave = tid >> 6, lane = tid & 63;
    int quad = lane >> 4, l15 = lane & 15;
    int m0 = blockIdx.y * 64, n0 = blockIdx.x * 128;
    int wm = (wave >> 1) * 32, wn = (wave & 1) * 64;
    int grow = lane >> 2, gcol = (lane & 3) * 8;
    const int K = DMODEL;
    f32x4 acc[2][4] = {};

    for (int k0 = 0; k0 < K; k0 += 32) {
        __syncthreads();
        gll16(&A[(m0 + wave * 16 + grow) * K + k0 + gcol], &As[wave * 16][0]);
#pragma unroll
        for (int ps = 0; ps < 2; ps++) {
            int row = ps * 64 + wave * 16;
            gll16(&Bt[(n0 + row + grow) * K + k0 + gcol], &Bs[row][0]);
        }
        __syncthreads();
        bf16x8 af[2], bfr[4];
#pragma unroll
        for (int mi = 0; mi < 2; mi++)
            af[mi] = *(const bf16x8*)&As[wm + mi * 16 + l15][quad * 8];
#pragma unroll
        for (int ni = 0; ni < 4; ni++)
            bfr[ni] = *(const bf16x8*)&Bs[wn + ni * 16 + l15][quad * 8];
#pragma unroll
        for (int mi = 0; mi < 2; mi++)
#pragma unroll
            for (int ni = 0; ni < 4; ni++)
                acc[mi][ni] = __builtin_amdgcn_mfma_f32_16x16x32_bf16(
                    af[mi], bfr[ni], acc[mi][ni], 0, 0, 0);
    }

#pragma unroll
    for (int mi = 0; mi < 2; mi++)
#pragma unroll
        for (int ni = 0; ni < 4; ni++)
#pragma unroll
            for (int rg = 0; rg < 4; rg++) {
                int m = m0 + wm + mi * 16 + quad * 4 + rg;
                int n = n0 + wn + ni * 16 + l15;
                out[(size_t)m * DMODEL + n] = acc[mi][ni][rg];
            }
}

// ---------------------------------------------------------------------------
// Flash attention v5. Q/K merged layout [b*2048+s][h*64+d] (hi/lo),
// V^T [bh][d][s]. Output attnb merged [b*2048+s][h*64+d] (coalesced).
// ---------------------------------------------------------------------------
__global__ __launch_bounds__(256, 4) void flash_attn(const __bf16* __restrict__ Qhi,
                                                     const __bf16* __restrict__ Qlo,
                                                     const __bf16* __restrict__ Khi,
                                                     const __bf16* __restrict__ Klo,
                                                     const __bf16* __restrict__ Vt,
                                                     __bf16* __restrict__ attn) {
    int id = blockIdx.x;
    int xcd = id & 7, which = id >> 3;
    int bh  = xcd + 8 * (which & 3);
    int p   = which >> 2;
    int b = bh >> 4, h = bh & 15;
    const __bf16* Qh_hi = Qhi + (size_t)b * S_LEN * DMODEL + h * HDIM;
    const __bf16* Qh_lo = Qlo + (size_t)b * S_LEN * DMODEL + h * HDIM;
    const __bf16* Kh_hi = Khi + (size_t)b * S_LEN * DMODEL + h * HDIM;
    const __bf16* Kh_lo = Klo + (size_t)b * S_LEN * DMODEL + h * HDIM;
    const __bf16* Vh    = Vt  + (size_t)bh * HDIM * S_LEN;

    int tid = threadIdx.x, wave = tid >> 6, lane = tid & 63;
    int quad = lane >> 4, l15 = lane & 15;
    int t1 = p, t2 = 31 - p;
    int n1 = t1 + 1;                       // iters for tile1; total always 33

    __shared__ __bf16 KhF[8 * 64 * 8];
    __shared__ __bf16 KlF[8 * 64 * 8];
    __shared__ __bf16 VF [8 * 64 * 8];
    __shared__ __bf16 Ps[4][16][72];

    int c1  = tid >> 6, key = tid & 63;
    int inner = (c1 * 16 + (key & 15)) * 8;
    int rK    = (key >> 4);
    int kdst0 = rK * 512 + inner, kdst1 = (4 + rK) * 512 + inner;
    const __bf16* vrow = Vh + (size_t)key * S_LEN;   // dim = key var

    int q0w = t1 * 64 + wave * 16;
    bf16x8 aqh0 = *(const bf16x8*)&Qh_hi[(size_t)(q0w + l15) * DMODEL + quad * 8];
    bf16x8 aqh1 = *(const bf16x8*)&Qh_hi[(size_t)(q0w + l15) * DMODEL + 32 + quad * 8];
    bf16x8 aql0 = *(const bf16x8*)&Qh_lo[(size_t)(q0w + l15) * DMODEL + quad * 8];
    bf16x8 aql1 = *(const bf16x8*)&Qh_lo[(size_t)(q0w + l15) * DMODEL + 32 + quad * 8];

    bf16x8 ones;
#pragma unroll
    for (int j = 0; j < 8; j++) ones[j] = (__bf16)1.0f;

    uint4 pk0, pk1, pl0, pl1, pv0, pv1;
    {   // prefetch tile kt=0
        const __bf16* sk = Kh_hi + (size_t)key * DMODEL;
        const __bf16* sl = Kh_lo + (size_t)key * DMODEL;
        pk0 = *(const uint4*)(sk + c1 * 8); pk1 = *(const uint4*)(sk + c1 * 8 + 32);
        pl0 = *(const uint4*)(sl + c1 * 8); pl1 = *(const uint4*)(sl + c1 * 8 + 32);
        pv0 = *(const uint4*)(vrow + c1 * 8); pv1 = *(const uint4*)(vrow + c1 * 8 + 32);
    }

    float m[4] = {-3e38f, -3e38f, -3e38f, -3e38f};
    f32x4 o[4] = {};
    f32x4 ol = {};
    int qrb = q0w + quad * 4;

    for (int i = 0; i < 33; i++) {
        int kt   = (i < n1) ? i : i - n1;
        int key0 = kt * 64;
        bool diag = (i == n1 - 1) || (i == 32);

        __syncthreads();
        *(uint4*)&KhF[kdst0] = pk0;  *(uint4*)&KhF[kdst1] = pk1;
        *(uint4*)&KlF[kdst0] = pl0;  *(uint4*)&KlF[kdst1] = pl1;
        *(uint4*)&VF [kdst0] = pv0;  *(uint4*)&VF [kdst1] = pv1;
        __syncthreads();

        if (i + 1 < 33) {
            int ktn   = (i + 1 < n1) ? i + 1 : i + 1 - n1;
            int key0n = ktn * 64;
            const __bf16* sk = Kh_hi + (size_t)(key0n + key) * DMODEL;
            const __bf16* sl = Kh_lo + (size_t)(key0n + key) * DMODEL;
            pk0 = *(const uint4*)(sk + c1 * 8); pk1 = *(const uint4*)(sk + c1 * 8 + 32);
            pl0 = *(const uint4*)(sl + c1 * 8); pl1 = *(const uint4*)(sl + c1 * 8 + 32);
            pv0 = *(const uint4*)(vrow + key0n + c1 * 8);
            pv1 = *(const uint4*)(vrow + key0n + c1 * 8 + 32);
        }

        // ---- S(log2 domain) = Q K^T, split-bf16: hi.hi + hi.lo + lo.hi
        f32x4 sc[4] = {};
#pragma unroll
        for (int ni = 0; ni < 4; ni++) {
            bf16x8 kh0 = *(const bf16x8*)&KhF[(ni * 64 + lane) * 8];
            bf16x8 kh1 = *(const bf16x8*)&KhF[((4 + ni) * 64 + lane) * 8];
            bf16x8 kl0 = *(const bf16x8*)&KlF[(ni * 64 + lane) * 8];
            bf16x8 kl1 = *(const bf16x8*)&KlF[((4 + ni) * 64 + lane) * 8];
            sc[ni] = __builtin_amdgcn_mfma_f32_16x16x32_bf16(aqh0, kh0, sc[ni], 0, 0, 0);
            sc[ni] = __builtin_amdgcn_mfma_f32_16x16x32_bf16(aqh1, kh1, sc[ni], 0, 0, 0);
            sc[ni] = __builtin_amdgcn_mfma_f32_16x16x32_bf16(aqh0, kl0, sc[ni], 0, 0, 0);
            sc[ni] = __builtin_amdgcn_mfma_f32_16x16x32_bf16(aqh1, kl1, sc[ni], 0, 0, 0);
            sc[ni] = __builtin_amdgcn_mfma_f32_16x16x32_bf16(aql0, kh0, sc[ni], 0, 0, 0);
            sc[ni] = __builtin_amdgcn_mfma_f32_16x16x32_bf16(aql1, kh1, sc[ni], 0, 0, 0);
        }

        if (diag) {
#pragma unroll
            for (int ni = 0; ni < 4; ni++) {
                int keyi = key0 + ni * 16 + l15;
#pragma unroll
                for (int rg = 0; rg < 4; rg++)
                    if (keyi > qrb + rg) sc[ni][rg] = -1e30f;
            }
        }

#pragma unroll
        for (int rg = 0; rg < 4; rg++) {
            float mx = fmaxf(fmaxf(sc[0][rg], sc[1][rg]),
                             fmaxf(sc[2][rg], sc[3][rg]));
#pragma unroll
            for (int mm = 1; mm < 16; mm <<= 1)
                mx = fmaxf(mx, __shfl_xor(mx, mm, 64));
            float mnew  = fmaxf(m[rg], mx);
            float alpha = __builtin_amdgcn_exp2f(m[rg] - mnew);
            m[rg] = mnew;
#pragma unroll
            for (int ni = 0; ni < 4; ni++) {
                float px = __builtin_amdgcn_exp2f(sc[ni][rg] - mnew);
                Ps[wave][quad * 4 + rg][ni * 16 + l15] = (__bf16)px;
            }
            ol[rg] *= alpha;
#pragma unroll
            for (int ni = 0; ni < 4; ni++)
                o[ni][rg] *= alpha;
        }

#pragma unroll
        for (int step = 0; step < 2; step++) {
            bf16x8 ap = *(const bf16x8*)&Ps[wave][l15][step * 32 + quad * 8];
            ol = __builtin_amdgcn_mfma_f32_16x16x32_bf16(ap, ones, ol, 0, 0, 0);
#pragma unroll
            for (int ni = 0; ni < 4; ni++) {
                bf16x8 bv = *(const bf16x8*)&VF[((step * 4 + ni) * 64 + lane) * 8];
                o[ni] = __builtin_amdgcn_mfma_f32_16x16x32_bf16(ap, bv, o[ni], 0, 0, 0);
            }
        }

        if (diag) {
#pragma unroll
            for (int rg = 0; rg < 4; rg++) {
                float inv = 1.0f / ol[rg];
                int q = q0w + quad * 4 + rg;
#pragma unroll
                for (int ni = 0; ni < 4; ni++) {
                    attn[((size_t)b * S_LEN + q) * DMODEL + h * HDIM + ni * 16 + l15] =
                        (__bf16)(o[ni][rg] * inv);
                }
                m[rg] = -3e38f;
            }
#pragma unroll
            for (int ni = 0; ni < 4; ni++) o[ni] = (f32x4){0.f, 0.f, 0.f, 0.f};
            ol = (f32x4){0.f, 0.f, 0.f, 0.f};
            if (i == n1 - 1) {
                q0w = t2 * 64 + wave * 16;
                qrb = q0w + quad * 4;
                aqh0 = *(const bf16x8*)&Qh_hi[(size_t)(q0w + l15) * DMODEL + quad * 8];
                aqh1 = *(const bf16x8*)&Qh_hi[(size_t)(q0w + l15) * DMODEL + 32 + quad * 8];
                aql0 = *(const bf16x8*)&Qh_lo[(size_t)(q0w + l15) * DMODEL + quad * 8];
                aql1 = *(const bf16x8*)&Qh_lo[(size_t)(q0w + l15) * DMODEL + 32 + quad * 8];
            }
        }
    }
}

// ---------------------------------------------------------------------------
extern "C" void kernel_launch(void* const* d_in, const int* in_sizes, int n_in,
                              void* d_out, int out_size, void* d_ws, size_t ws_size,
                              hipStream_t stream) {
    const float* x  = (const float*)d_in[0];
    const float* qw = (const float*)d_in[1];
    const float* kw = (const float*)d_in[2];
    const float* vw = (const float*)d_in[3];
    const float* ow = (const float*)d_in[4];

    char* ws = (char*)d_ws;
    const size_t MB = 1024 * 1024;
    __bf16* xhi   = (__bf16*)(ws);             //  8 MB  [4096,1024]
    __bf16* xlo   = (__bf16*)(ws + 8 * MB);    //  8 MB  (reused as attnb later)
    __bf16* qwthi = (__bf16*)(ws + 16 * MB);   //  2 MB each
    __bf16* qwtlo = (__bf16*)(ws + 18 * MB);
    __bf16* kwthi = (__bf16*)(ws + 20 * MB);
    __bf16* kwtlo = (__bf16*)(ws + 22 * MB);
    __bf16* vwt   = (__bf16*)(ws + 24 * MB);
    __bf16* owt   = (__bf16*)(ws + 26 * MB);
    __bf16* Qhi_b = (__bf16*)(ws + 28 * MB);   //  8 MB  merged [B*S][D]
    __bf16* Qlo_b = (__bf16*)(ws + 36 * MB);
    __bf16* Khi_b = (__bf16*)(ws + 44 * MB);
    __bf16* Klo_b = (__bf16*)(ws + 52 * MB);
    __bf16* Vtb   = (__bf16*)(ws + 60 * MB);   //  8 MB  [B,H,64,S]
    __bf16* attnb = xlo;                       //  alias: xlo dead after QKV GEMMs

    conv_split<<<4096, 256, 0, stream>>>(x, xhi, xlo, 4096 * 1024 / 4);
    transpose_all<<<dim3(32, 32, 4), 256, 0, stream>>>(
        qw, kw, vw, ow, qwthi, qwtlo, kwthi, kwtlo, vwt, owt);

    qkv_gemm<<<dim3(8, 32, 3), 256, 0, stream>>>(
        xhi, xlo, qwthi, qwtlo, kwthi, kwtlo, vwt,
        Qhi_b, Qlo_b, Khi_b, Klo_b, Vtb);

    flash_attn<<<512, 256, 0, stream>>>(Qhi_b, Qlo_b, Khi_b, Klo_b, Vtb, attnb);

    out_gemm<<<dim3(8, 64), 256, 0, stream>>>(attnb, owt, (float*)d_out);
}